// Round 11
// baseline (3068.507 us; speedup 1.0000x reference)
//
#include <hip/hip_runtime.h>

// ---------------------------------------------------------------------------
// FrontierVerifierExpertHead — round 11
// moe8_k: barrier-free, LDS-free MoE — B fragments and down coefficients are
// loaded straight from global (cvtup's kq-major layout == MFMA fragment
// layout). Everything else identical to round 10 (best config, 2770 us).
// ---------------------------------------------------------------------------

constexpr int NI      = 4096;
constexpr int DIM     = 256;
constexpr int ODIM    = 10;
constexpr int NMEM_   = 32;
constexpr int NSTEPS_ = 6;
constexpr int NEXPERT_= 12;
constexpr int MAXE    = 4608;
constexpr int TOTCOL  = 46592;  // 12 experts tight + shared 3072 + aux 4096
#define SCL 0.0625f             // 256^-0.5

__constant__ int GCNT[14]   = {8,10,12,14,16,9,11,13,15,18,12,16,12,16};
__constant__ int GSTART[14] = {0,8,18,30,44,60,69,80,93,108,126,138,154,166};
__constant__ int CCNT[14]   = {32,40,48,56,64,36,44,52,60,72,48,64,48,64};
__constant__ int ZCOL[14]   = {0,2048,4608,7680,11264,15360,17664,20480,
                               23808,27648,32256,35328,39424,42496};

typedef __attribute__((ext_vector_type(8))) short short8v;
typedef __attribute__((ext_vector_type(4))) float float4v;
typedef __attribute__((ext_vector_type(4))) unsigned short ushort4v;

// ----------------------------- device helpers ------------------------------

__device__ __forceinline__ float wred_sum(float v){
  #pragma unroll
  for (int m = 32; m > 0; m >>= 1) v += __shfl_xor(v, m, 64);
  return v;
}
__device__ __forceinline__ float wred_max(float v){
  #pragma unroll
  for (int m = 32; m > 0; m >>= 1) v = fmaxf(v, __shfl_xor(v, m, 64));
  return v;
}
// ---- fast inline transcendentals (no OCML calls) ----
__device__ __forceinline__ float sigm(float x){ return 1.f/(1.f + __expf(-x)); }
__device__ __forceinline__ float tanh_f(float x){
  float e = __expf(2.f*fabsf(x));
  float r = 1.f - 2.f/(e + 1.f);
  return copysignf(r, x);
}
__device__ __forceinline__ float erf_f(float x){
  float ax = fabsf(x);
  float t = 1.f/fmaf(0.3275911f, ax, 1.f);
  float p = t*(0.254829592f + t*(-0.284496736f + t*(1.421413741f +
            t*(-1.453152027f + t*1.061405429f))));
  float r = 1.f - p*__expf(-ax*ax);
  return copysignf(r, x);
}
__device__ __forceinline__ float geluf(float x){
  return 0.5f*x*(1.f + erf_f(x*0.70710678118654752f));
}
__device__ __forceinline__ float softplusf(float x){
  return fmaxf(x, 0.f) + __logf(1.f + __expf(-fabsf(x)));
}
__device__ __forceinline__ unsigned short f2b(float f){   // fp32 -> bf16 RNE
  unsigned u = __float_as_uint(f);
  u = u + 0x7FFFu + ((u >> 16) & 1u);
  return (unsigned short)(u >> 16);
}
__device__ __forceinline__ float b2f(unsigned short u){
  return __uint_as_float((unsigned)u << 16);
}
__device__ __forceinline__ float dot256f(const float* __restrict__ a,
                                         const float* __restrict__ w, float s){
  for (int k = 0; k < DIM; k += 4){
    float4 av = *(const float4*)&a[k];
    float4 wv = *(const float4*)&w[k];
    s = fmaf(av.x,wv.x, fmaf(av.y,wv.y, fmaf(av.z,wv.z, fmaf(av.w,wv.w, s))));
  }
  return s;
}
__device__ __forceinline__ void ln10(const float* p, const float* s, const float* b, float* o){
  float mu = 0.f;
  #pragma unroll
  for (int i=0;i<ODIM;i++) mu += p[i];
  mu *= 0.1f;
  float var = 0.f;
  #pragma unroll
  for (int i=0;i<ODIM;i++){ float d = p[i]-mu; var += d*d; }
  var *= 0.1f;
  float rs = 1.f/sqrtf(var + 1e-5f);
  #pragma unroll
  for (int i=0;i<ODIM;i++) o[i] = (p[i]-mu)*rs*s[i] + b[i];
}

// ------------------------- fp32 -> bf16 converter --------------------------
__global__ __launch_bounds__(256)
void cvt_k(const float* __restrict__ in, unsigned short* __restrict__ out, int n)
{
  int idx = (blockIdx.x*256 + threadIdx.x)*4;
  if (idx + 3 < n){
    float4 v = *(const float4*)&in[idx];
    ushort4v t; t[0]=f2b(v.x); t[1]=f2b(v.y); t[2]=f2b(v.z); t[3]=f2b(v.w);
    *(ushort4v*)&out[idx] = t;
  }
}

// ----------------- up-weight convert to tight kq-major bf16 ----------------
__global__ __launch_bounds__(512)
void cvtup_k(const float* __restrict__ exp_up, const float* __restrict__ shared_up,
             const float* __restrict__ aux_up, short* __restrict__ upb)
{
  int chunk = blockIdx.x;
  int z = 0, crem = chunk;
  while (crem >= CCNT[z]){ crem -= CCNT[z]; z++; }
  const float* src;
  if (z < 12)       src = exp_up + (size_t)z*MAXE*DIM;
  else if (z == 12) src = shared_up;
  else              src = aux_up;
  int colbase = crem*64;
  short* dst = upb + (size_t)chunk*16384;
  int t = threadIdx.x;
  int c = t >> 3, kb = (t & 7)*32;
  const float* srow = src + (size_t)(colbase + c)*DIM + kb;
  #pragma unroll
  for (int j = 0; j < 4; j++){
    float4 f0 = *(const float4*)&srow[j*8];
    float4 f1 = *(const float4*)&srow[j*8+4];
    short8v s;
    s[0]=(short)f2b(f0.x); s[1]=(short)f2b(f0.y); s[2]=(short)f2b(f0.z); s[3]=(short)f2b(f0.w);
    s[4]=(short)f2b(f1.x); s[5]=(short)f2b(f1.y); s[6]=(short)f2b(f1.z); s[7]=(short)f2b(f1.w);
    int kq = (t & 7)*4 + j;
    *(short8v*)&dst[((size_t)kq*64 + c)*8] = s;
  }
}

// ----------------------------- tiled fp32 GEMM (64x64) ---------------------
// EPI: 0 none | 1 +bias | 3 +bias+R | 6 split col<256 -> C(+bias) else C2
template<int EPI>
__global__ __launch_bounds__(256)
void gemm_k(const float* __restrict__ A, const float* __restrict__ W,
            const float* __restrict__ bias, const float* __restrict__ R,
            float* __restrict__ C, float* __restrict__ C2, int N, int K)
{
  __shared__ float As[32][68];
  __shared__ float Ws[32][68];
  const int bm = blockIdx.y*64, bn = blockIdx.x*64;
  const int tid = threadIdx.x;
  const int tx = tid & 15, ty = tid >> 4;
  const int lrow = tid >> 2, lkq = (tid & 3) * 8;
  float acc[4][4] = {};
  for (int k0 = 0; k0 < K; k0 += 32){
    #pragma unroll
    for (int h = 0; h < 2; ++h){
      int kk = lkq + h*4;
      float4 va = *(const float4*)&A[(size_t)(bm+lrow)*K + k0 + kk];
      float4 vw = *(const float4*)&W[(size_t)(bn+lrow)*K + k0 + kk];
      As[kk+0][lrow]=va.x; As[kk+1][lrow]=va.y; As[kk+2][lrow]=va.z; As[kk+3][lrow]=va.w;
      Ws[kk+0][lrow]=vw.x; Ws[kk+1][lrow]=vw.y; Ws[kk+2][lrow]=vw.z; Ws[kk+3][lrow]=vw.w;
    }
    __syncthreads();
    #pragma unroll
    for (int kk = 0; kk < 32; ++kk){
      float4 a4 = *(const float4*)&As[kk][ty*4];
      float4 b4 = *(const float4*)&Ws[kk][tx*4];
      float av[4] = {a4.x,a4.y,a4.z,a4.w};
      float bv[4] = {b4.x,b4.y,b4.z,b4.w};
      #pragma unroll
      for (int i=0;i<4;i++)
        #pragma unroll
        for (int j=0;j<4;j++) acc[i][j] = fmaf(av[i], bv[j], acc[i][j]);
    }
    __syncthreads();
  }
  #pragma unroll
  for (int i=0;i<4;i++){
    int r = bm + ty*4 + i;
    #pragma unroll
    for (int j=0;j<4;j++){
      int c = bn + tx*4 + j;
      float v = acc[i][j];
      if constexpr (EPI==0){ C[(size_t)r*N + c] = v; }
      else if constexpr (EPI==1){ C[(size_t)r*N + c] = v + bias[c]; }
      else if constexpr (EPI==3){ C[(size_t)r*N + c] = v + bias[c] + R[(size_t)r*N + c]; }
      else if constexpr (EPI==6){
        if (c < 256) C[(size_t)r*256 + c] = v + bias[c];
        else C2[(size_t)r*256 + (c-256)] = v;
      }
    }
  }
}

// ------------------- fp32 128x64 tile GEMM, gelu epilogue ------------------
__global__ __launch_bounds__(256)
void gemm_rc1_k(const float* __restrict__ A, const float* __restrict__ W,
                const float* __restrict__ bias, float* __restrict__ C,
                int N, int K)
{
  __shared__ float As[32][132];
  __shared__ float Ws[32][68];
  const int bm = blockIdx.y*128, bn = blockIdx.x*64;
  const int tid = threadIdx.x;
  const int tx = tid & 15, ty = tid >> 4;
  const int arow = tid >> 1, ak = (tid & 1)*16;
  const int brow = tid >> 2, bk = (tid & 3)*8;
  float acc[8][4] = {};
  for (int k0 = 0; k0 < K; k0 += 32){
    float4 a0 = *(const float4*)&A[(size_t)(bm+arow)*K + k0 + ak];
    float4 a1 = *(const float4*)&A[(size_t)(bm+arow)*K + k0 + ak + 4];
    float4 a2 = *(const float4*)&A[(size_t)(bm+arow)*K + k0 + ak + 8];
    float4 a3 = *(const float4*)&A[(size_t)(bm+arow)*K + k0 + ak + 12];
    float4 b0 = *(const float4*)&W[(size_t)(bn+brow)*K + k0 + bk];
    float4 b1 = *(const float4*)&W[(size_t)(bn+brow)*K + k0 + bk + 4];
    As[ak+ 0][arow]=a0.x; As[ak+ 1][arow]=a0.y; As[ak+ 2][arow]=a0.z; As[ak+ 3][arow]=a0.w;
    As[ak+ 4][arow]=a1.x; As[ak+ 5][arow]=a1.y; As[ak+ 6][arow]=a1.z; As[ak+ 7][arow]=a1.w;
    As[ak+ 8][arow]=a2.x; As[ak+ 9][arow]=a2.y; As[ak+10][arow]=a2.z; As[ak+11][arow]=a2.w;
    As[ak+12][arow]=a3.x; As[ak+13][arow]=a3.y; As[ak+14][arow]=a3.z; As[ak+15][arow]=a3.w;
    Ws[bk+0][brow]=b0.x; Ws[bk+1][brow]=b0.y; Ws[bk+2][brow]=b0.z; Ws[bk+3][brow]=b0.w;
    Ws[bk+4][brow]=b1.x; Ws[bk+5][brow]=b1.y; Ws[bk+6][brow]=b1.z; Ws[bk+7][brow]=b1.w;
    __syncthreads();
    #pragma unroll
    for (int kk = 0; kk < 32; ++kk){
      float a8[8];
      *(float4*)&a8[0] = *(const float4*)&As[kk][ty*8];
      *(float4*)&a8[4] = *(const float4*)&As[kk][ty*8+4];
      float4 b4 = *(const float4*)&Ws[kk][tx*4];
      float bv[4] = {b4.x,b4.y,b4.z,b4.w};
      #pragma unroll
      for (int i=0;i<8;i++)
        #pragma unroll
        for (int j=0;j<4;j++) acc[i][j] = fmaf(a8[i], bv[j], acc[i][j]);
    }
    __syncthreads();
  }
  #pragma unroll
  for (int i=0;i<8;i++){
    int r = bm + ty*8 + i;
    #pragma unroll
    for (int j=0;j<4;j++){
      int c = bn + tx*4 + j;
      C[(size_t)r*N + c] = geluf(acc[i][j] + bias[c]);
    }
  }
}

// ------------------------------ bf16 MFMA GEMM -----------------------------
// EPI 0: gelu(acc+bias) -> bf16 Cb ; EPI 1: acc+bias+R -> f32 Cf
template<int EPI>
__global__ __launch_bounds__(256)
void bgemm_k(const short* __restrict__ A, const short* __restrict__ B,
             const float* __restrict__ bias, const float* __restrict__ R,
             float* __restrict__ Cf, unsigned short* __restrict__ Cb,
             int N, int K)
{
  __shared__ short As[128][40];
  __shared__ short Bsm[64][40];
  const int bm = blockIdx.y*128, bn = blockIdx.x*64;
  const int tid = threadIdx.x;
  const int wave = tid >> 6, lane = tid & 63;
  const int l15 = lane & 15, lg = lane >> 4;
  const int ar = tid >> 1, ah = tid & 1;
  float4v acc[2][4] = {};
  for (int k0 = 0; k0 < K; k0 += 32){
    __syncthreads();
    { const short* src = A + (size_t)(bm+ar)*K + k0 + ah*16;
      short8v v0 = *(const short8v*)src;
      short8v v1 = *(const short8v*)(src+8);
      *(short8v*)&As[ar][ah*16]   = v0;
      *(short8v*)&As[ar][ah*16+8] = v1; }
    if (tid < 128){
      const short* src = B + (size_t)(bn+ar)*K + k0 + ah*16;
      short8v v0 = *(const short8v*)src;
      short8v v1 = *(const short8v*)(src+8);
      *(short8v*)&Bsm[ar][ah*16]   = v0;
      *(short8v*)&Bsm[ar][ah*16+8] = v1; }
    __syncthreads();
    short8v bfr[4];
    #pragma unroll
    for (int nt = 0; nt < 4; nt++)
      bfr[nt] = *(const short8v*)&Bsm[nt*16 + l15][lg*8];
    #pragma unroll
    for (int mt = 0; mt < 2; mt++){
      short8v a = *(const short8v*)&As[wave*32 + mt*16 + l15][lg*8];
      #pragma unroll
      for (int nt = 0; nt < 4; nt++)
        acc[mt][nt] = __builtin_amdgcn_mfma_f32_16x16x32_bf16(a, bfr[nt], acc[mt][nt], 0, 0, 0);
    }
  }
  #pragma unroll
  for (int mt = 0; mt < 2; mt++)
    #pragma unroll
    for (int nt = 0; nt < 4; nt++)
      #pragma unroll
      for (int reg = 0; reg < 4; reg++){
        int row = bm + wave*32 + mt*16 + lg*4 + reg;
        int col = bn + nt*16 + l15;
        float v = acc[mt][nt][reg];
        if constexpr (EPI==0){
          v = geluf(v + bias[col]);
          Cb[(size_t)row*N + col] = f2b(v);
        } else {
          v = v + bias[col] + R[(size_t)row*N + col];
          Cf[(size_t)row*N + col] = v;
        }
      }
}

// ---- MoE (gathered) / shared / aux (dense): LDS-free, barrier-free MFMA ----
// cvtup's kq-major chunk layout == MFMA B-fragment layout, so B fragments are
// loaded straight from global into registers (coalesced 16B/lane). down coeffs
// are loaded per-o (coalesced per 16-lane group, L2-resident). No LDS.
__global__ __launch_bounds__(512)
void moe8_k(const unsigned short* __restrict__ curb, const unsigned short* __restrict__ xb,
            const short* __restrict__ upb,
            const float* __restrict__ exp_down, const float* __restrict__ shared_down,
            const float* __restrict__ aux_down,
            const int* __restrict__ idxl, const int* __restrict__ cnt,
            unsigned short* __restrict__ part)
{
  int gy = blockIdx.y, z = 0;
  while (gy >= GCNT[z]){ gy -= GCNT[z]; z++; }
  const int n = (z < 12) ? cnt[z] : NI;
  const int bm = blockIdx.x*128;
  if (bm >= n) return;
  const int g = GSTART[z] + gy;
  const int localcol = gy*256;
  int act, dstride; const float* down;
  if (z < 12){ act = z & 7; down = exp_down + (size_t)z*ODIM*MAXE; dstride = MAXE; }
  else if (z == 12){ act = 0; down = shared_down; dstride = 3072; }
  else { act = 1; down = aux_down; dstride = 4096; }
  const unsigned short* X = (z < 12) ? curb : xb;
  const int tid = threadIdx.x, wave = tid >> 6, lane = tid & 63;
  const int l15 = lane & 15, lg = lane >> 4;

  int slotA = bm + wave*16 + l15;
  int itemA;
  if (z < 12) itemA = idxl[(size_t)z*NI + ((slotA < n) ? slotA : (n-1))];
  else        itemA = slotA;

  short8v afrag[8];
  { const unsigned short* xr = X + (size_t)itemA*DIM;
    #pragma unroll
    for (int ks = 0; ks < 8; ks++)
      afrag[ks] = *(const short8v*)&xr[ks*32 + lg*8];
  }
  float racc[4][10];
  #pragma unroll
  for (int r = 0; r < 4; r++)
    #pragma unroll
    for (int o = 0; o < 10; o++) racc[r][o] = 0.f;

  const int gchunk0 = (ZCOL[z] + localcol) >> 6;

  #pragma unroll
  for (int ch = 0; ch < 4; ++ch){
    const short* chunk = upb + (size_t)(gchunk0 + ch)*16384;
    const int cb = localcol + ch*64;
    float4v acc[4] = {};
    #pragma unroll
    for (int ks = 0; ks < 8; ks++)
      #pragma unroll
      for (int nt = 0; nt < 4; nt++){
        int u = (ks*4 + lg)*64 + nt*16 + l15;
        short8v b = *(const short8v*)&chunk[(size_t)u*8];
        acc[nt] = __builtin_amdgcn_mfma_f32_16x16x32_bf16(afrag[ks], b, acc[nt], 0, 0, 0);
      }
    // activation: ONE uniform runtime switch, unrolled bodies (static idx only)
    float hv[4][4];
    switch(act){
      case 0:
        #pragma unroll
        for (int nt=0;nt<4;nt++)
          #pragma unroll
          for (int r=0;r<4;r++){ float xx=acc[nt][r]; hv[nt][r]=xx*sigm(xx); }
        break;
      case 1:
        #pragma unroll
        for (int nt=0;nt<4;nt++)
          #pragma unroll
          for (int r=0;r<4;r++){ hv[nt][r]=geluf(acc[nt][r]); }
        break;
      case 2:
        #pragma unroll
        for (int nt=0;nt<4;nt++)
          #pragma unroll
          for (int r=0;r<4;r++){ float xx=acc[nt][r]; hv[nt][r]=xx*tanh_f(softplusf(xx)); }
        break;
      case 3:
        #pragma unroll
        for (int nt=0;nt<4;nt++)
          #pragma unroll
          for (int r=0;r<4;r++){ hv[nt][r]=fmaxf(acc[nt][r],0.f); }
        break;
      case 4:
        #pragma unroll
        for (int nt=0;nt<4;nt++)
          #pragma unroll
          for (int r=0;r<4;r++){
            const float l=1.0507009873554805f, al=1.6732632423543772f;
            float xx=acc[nt][r];
            hv[nt][r] = xx>0.f ? l*xx : l*al*(__expf(xx)-1.f);
          }
        break;
      case 5:
        #pragma unroll
        for (int nt=0;nt<4;nt++)
          #pragma unroll
          for (int r=0;r<4;r++){ hv[nt][r]=tanh_f(acc[nt][r]); }
        break;
      case 6:
        #pragma unroll
        for (int nt=0;nt<4;nt++)
          #pragma unroll
          for (int r=0;r<4;r++){ hv[nt][r]=softplusf(acc[nt][r]); }
        break;
      default:
        #pragma unroll
        for (int nt=0;nt<4;nt++)
          #pragma unroll
          for (int r=0;r<4;r++){ float xx=acc[nt][r]; hv[nt][r]= xx>0.f ? xx : __expf(xx)-1.f; }
        break;
    }
    #pragma unroll
    for (int nt = 0; nt < 4; nt++){
      int col = cb + nt*16 + l15;
      float dv[10];
      #pragma unroll
      for (int o = 0; o < 10; o++) dv[o] = down[(size_t)o*dstride + col];
      #pragma unroll
      for (int o = 0; o < 10; o++)
        #pragma unroll
        for (int r = 0; r < 4; r++)
          racc[r][o] = fmaf(hv[nt][r], dv[o], racc[r][o]);
    }
  }
  #pragma unroll
  for (int r = 0; r < 4; r++)
    #pragma unroll
    for (int o = 0; o < 10; o++){
      float v = racc[r][o];
      v += __shfl_xor(v, 1, 64); v += __shfl_xor(v, 2, 64);
      v += __shfl_xor(v, 4, 64); v += __shfl_xor(v, 8, 64);
      racc[r][o] = v;
    }
  if (l15 == 0){
    #pragma unroll
    for (int r = 0; r < 4; r++){
      int slotW = bm + wave*16 + lg*4 + r;
      int itemW;
      if (z < 12) itemW = idxl[(size_t)z*NI + ((slotW < n) ? slotW : (n-1))];
      else        itemW = slotW;
      #pragma unroll
      for (int o = 0; o < 10; o++)
        part[((size_t)g*NI + itemW)*ODIM + o] = f2b(racc[r][o]);
    }
  }
}

// --------------------------- partials reduce 182 -> 14 ---------------------
__global__ __launch_bounds__(256)
void red_k(const unsigned short* __restrict__ part, float* __restrict__ expert_pre,
           float* __restrict__ shared_pre, float* __restrict__ aux_pre)
{
  int idx = blockIdx.x*256 + threadIdx.x;
  if (idx >= 14*NI*ODIM) return;
  int z = idx / (NI*ODIM), rem = idx - z*NI*ODIM;
  float s = 0.f;
  int g0 = GSTART[z], gn = GCNT[z];
  for (int g2 = 0; g2 < gn; g2++)
    s += b2f(part[(size_t)(g0 + g2)*NI*ODIM + rem]);
  if (z < 12) expert_pre[(size_t)z*NI*ODIM + rem] = s;
  else if (z == 12) shared_pre[rem] = s;
  else aux_pre[rem] = s;
}

// ----------------------- small one-off matrix products ---------------------
__global__ void atb_k(const float* __restrict__ A, const float* __restrict__ B,
                      float* __restrict__ C, int M, int I, int J)
{
  int idx = blockIdx.x*256 + threadIdx.x;
  if (idx >= I*J) return;
  int i = idx / J, j = idx - i*J;
  float s = 0.f;
  for (int m = 0; m < M; m++) s = fmaf(A[(size_t)m*I+i], B[(size_t)m*J+j], s);
  C[idx] = s;
}
__global__ void ab_k(const float* __restrict__ A, const float* __restrict__ B,
                     float* __restrict__ C, int M, int K, int N)
{
  int idx = blockIdx.x*256 + threadIdx.x;
  if (idx >= M*N) return;
  int i = idx / N, j = idx - i*N;
  float s = 0.f;
  for (int k = 0; k < K; k++) s = fmaf(A[(size_t)i*K+k], B[(size_t)k*N+j], s);
  C[idx] = s;
}

// --------------------- LN (+up to 2 extra addends), D=256 ------------------
__global__ __launch_bounds__(256)
void ln3_k(const float* __restrict__ a, const float* __restrict__ b,
           const float* __restrict__ c, const float* __restrict__ lns,
           const float* __restrict__ lnb, float* __restrict__ xout,
           float* __restrict__ lnout, unsigned short* __restrict__ lnout_b)
{
  int item = blockIdx.x*4 + (threadIdx.x >> 6);
  int lane = threadIdx.x & 63;
  float4 v = ((const float4*)(a + (size_t)item*DIM))[lane];
  if (b){ float4 t = ((const float4*)(b + (size_t)item*DIM))[lane]; v.x+=t.x; v.y+=t.y; v.z+=t.z; v.w+=t.w; }
  if (c){ float4 t = ((const float4*)(c + (size_t)item*DIM))[lane]; v.x+=t.x; v.y+=t.y; v.z+=t.z; v.w+=t.w; }
  if (xout) ((float4*)(xout + (size_t)item*DIM))[lane] = v;
  float mu = wred_sum(v.x+v.y+v.z+v.w) * (1.f/DIM);
  float dx=v.x-mu, dy=v.y-mu, dz=v.z-mu, dw=v.w-mu;
  float var = wred_sum(dx*dx+dy*dy+dz*dz+dw*dw) * (1.f/DIM);
  float rs = 1.f/sqrtf(var + 1e-5f);
  float4 s4 = ((const float4*)lns)[lane];
  float4 b4 = ((const float4*)lnb)[lane];
  float4 o4 = make_float4(dx*rs*s4.x + b4.x, dy*rs*s4.y + b4.y,
                          dz*rs*s4.z + b4.z, dw*rs*s4.w + b4.w);
  if (lnout) ((float4*)(lnout + (size_t)item*DIM))[lane] = o4;
  if (lnout_b){
    ushort4v t; t[0]=f2b(o4.x); t[1]=f2b(o4.y); t[2]=f2b(o4.z); t[3]=f2b(o4.w);
    *(ushort4v*)(lnout_b + (size_t)item*DIM + lane*4) = t;
  }
}

// ----- memory read + softmax + factorized bank read + write-gate update ----
__global__ __launch_bounds__(256)
void memrw_k(const float* __restrict__ cur, const float* __restrict__ MK,
             const float* __restrict__ mem_vals, const float* __restrict__ wv_hist,
             const float* __restrict__ mem_wg_w, const float* __restrict__ mem_wg_b,
             float* __restrict__ a_state, float* __restrict__ c_state,
             float* __restrict__ mem_read, int step)
{
  __shared__ float smem[4][DIM];
  int wi = threadIdx.x >> 6;
  int item = blockIdx.x*4 + wi;
  int lane = threadIdx.x & 63;
  float v = -1e30f;
  if (lane < NMEM_)
    v = dot256f(cur + (size_t)item*DIM, MK + (size_t)lane*DIM, 0.f) * SCL;
  float m = wred_max(v);
  float e = (lane < NMEM_) ? __expf(v - m) : 0.f;
  float inv = 1.f / wred_sum(e);
  float attn = e * inv;
  float aval = 0.f;
  if (lane < NMEM_) aval = (step == 0) ? 1.f : a_state[(size_t)item*NMEM_ + lane];
  float wslot = attn * aval;
  float beta[NSTEPS_];
  #pragma unroll
  for (int t = 0; t < NSTEPS_; t++){
    beta[t] = 0.f;
    if (t < step){
      float cc = (lane < NMEM_) ? c_state[((size_t)item*NMEM_ + lane)*NSTEPS_ + t] : 0.f;
      beta[t] = wred_sum(attn * cc);
    }
  }
  float ax=0.f, ay=0.f, az=0.f, aw=0.f;
  #pragma unroll
  for (int s2 = 0; s2 < NMEM_; s2++){
    float ws = __shfl(wslot, s2, 64);
    float4 mv = ((const float4*)(mem_vals + (size_t)s2*DIM))[lane];
    ax = fmaf(ws, mv.x, ax); ay = fmaf(ws, mv.y, ay);
    az = fmaf(ws, mv.z, az); aw = fmaf(ws, mv.w, aw);
  }
  #pragma unroll
  for (int t = 0; t < NSTEPS_; t++){
    if (t < step){
      float4 h4 = ((const float4*)(wv_hist + ((size_t)t*NI + item)*DIM))[lane];
      ax = fmaf(beta[t], h4.x, ax); ay = fmaf(beta[t], h4.y, ay);
      az = fmaf(beta[t], h4.z, az); aw = fmaf(beta[t], h4.w, aw);
    }
  }
  float4 mr = make_float4(ax,ay,az,aw);
  ((float4*)(mem_read + (size_t)item*DIM))[lane] = mr;
  ((float4*)&smem[wi][0])[lane] = mr;
  __syncthreads();
  if (lane < NMEM_){
    const float* wr = mem_wg_w + (size_t)lane*2*DIM;
    float s = dot256f(cur + (size_t)item*DIM, wr, 0.f);
    s = dot256f(&smem[wi][0], wr + DIM, s);
    s += mem_wg_b[lane];
    float gte = sigm(s);
    int idx = item*NMEM_ + lane;
    float om = 1.f - gte;
    float a = (step == 0) ? 1.f : a_state[idx];
    a_state[idx] = a * om;
    float* c = c_state + (size_t)idx*NSTEPS_;
    #pragma unroll
    for (int t = 0; t < NSTEPS_; t++) if (t < step) c[t] *= om;
    c[step] = gte;
  }
}

// ------------------- bank attention (scores+softmax+wsum) ------------------
__global__ __launch_bounds__(256)
void bankattn_k(const float* __restrict__ q2, const float* __restrict__ bank,
                float* __restrict__ wsum, int t)
{
  int item = blockIdx.x*4 + (threadIdx.x >> 6);
  int lane = threadIdx.x & 63;
  float4 q4 = ((const float4*)(q2 + (size_t)item*DIM))[lane];
  float sc[NSTEPS_];
  float4 bb[NSTEPS_];
  #pragma unroll
  for (int j = 0; j < NSTEPS_; j++){
    if (j < t){
      bb[j] = ((const float4*)(bank + ((size_t)j*NI + item)*DIM))[lane];
      sc[j] = wred_sum(q4.x*bb[j].x + q4.y*bb[j].y + q4.z*bb[j].z + q4.w*bb[j].w) * SCL;
    }
  }
  float mx = -1e30f;
  #pragma unroll
  for (int j = 0; j < NSTEPS_; j++) if (j < t) mx = fmaxf(mx, sc[j]);
  float se = 0.f;
  #pragma unroll
  for (int j = 0; j < NSTEPS_; j++) if (j < t){ sc[j] = __expf(sc[j]-mx); se += sc[j]; }
  float inv = 1.f/se;
  float ax=0.f, ay=0.f, az=0.f, aw=0.f;
  #pragma unroll
  for (int j = 0; j < NSTEPS_; j++){
    if (j < t){
      float a = sc[j]*inv;
      ax = fmaf(a, bb[j].x, ax); ay = fmaf(a, bb[j].y, ay);
      az = fmaf(a, bb[j].z, az); aw = fmaf(a, bb[j].w, aw);
    }
  }
  ((float4*)(wsum + (size_t)item*DIM))[lane] = make_float4(ax,ay,az,aw);
}

// -------- SSM adapter + halting-weighted logits (one wave per item) --------
__global__ __launch_bounds__(256)
void ssmhalt_k(const float* __restrict__ cur_in, const float* __restrict__ mem_read,
               const float* __restrict__ depth_ctx,
               const float* __restrict__ ssm_in_w, const float* __restrict__ ssm_out_w,
               const float* __restrict__ ssm_decay,
               const float* __restrict__ halt_w, const float* __restrict__ halt_b,
               const float* __restrict__ mem_out_w, const float* __restrict__ depth_out_w,
               float* __restrict__ newcur, float* __restrict__ mem_logits,
               float* __restrict__ depth_logits, float* __restrict__ cum_halt, int step)
{
  __shared__ float sh48[4][48];
  int wi = threadIdx.x >> 6;
  int item = blockIdx.x*4 + wi;
  int lane = threadIdx.x & 63;
  const float* ci = cur_in + (size_t)item*DIM;
  if (lane < 48){
    float s = dot256f(ci, ssm_in_w + (size_t)lane*DIM, 0.f);
    sh48[wi][lane] = tanh_f(s) * sigm(ssm_decay[lane]);
  }
  __syncthreads();
  float4 nc = ((const float4*)ci)[lane];
  float o0 = nc.x, o1 = nc.y, o2 = nc.z, o3 = nc.w;
  const float* so = ssm_out_w + (size_t)(lane*4)*48;
  #pragma unroll 8
  for (int j = 0; j < 48; j++){
    float h = sh48[wi][j];
    o0 = fmaf(h, so[j],       o0);
    o1 = fmaf(h, so[48 + j],  o1);
    o2 = fmaf(h, so[96 + j],  o2);
    o3 = fmaf(h, so[144 + j], o3);
  }
  ((float4*)(newcur + (size_t)item*DIM))[lane] = make_float4(o0,o1,o2,o3);
  float4 hw = ((const float4*)(halt_w + (size_t)step*DIM))[lane];
  float hd = wred_sum(o0*hw.x + o1*hw.y + o2*hw.z + o3*hw.w);
  float halt = sigm(hd + halt_b[step]);
  float ch = cum_halt[item];
  float wstep = (1.f - ch) * halt;
  float4 m4 = ((const float4*)(mem_read + (size_t)item*DIM))[lane];
  float4 d4 = make_float4(0.f,0.f,0.f,0.f);
  if (step > 0) d4 = ((const float4*)(depth_ctx + (size_t)item*DIM))[lane];
  #pragma unroll
  for (int o = 0; o < ODIM; o++){
    float4 w4 = ((const float4*)(mem_out_w + (size_t)o*DIM))[lane];
    float s = wred_sum(m4.x*w4.x + m4.y*w4.y + m4.z*w4.z + m4.w*w4.w);
    if (lane == 0) mem_logits[(size_t)item*ODIM + o] += wstep * s;
    if (step > 0){
      float4 v4 = ((const float4*)(depth_out_w + (size_t)o*DIM))[lane];
      float s2 = wred_sum(d4.x*v4.x + d4.y*v4.y + d4.z*v4.z + d4.w*v4.w);
      if (lane == 0) depth_logits[(size_t)item*ODIM + o] += wstep * s2;
    }
  }
  if (lane == 0) cum_halt[item] = fminf(ch + halt, 1.f);
}

// --------------- router stage 1: 70 projections (flat, parallel) -----------
__global__ __launch_bounds__(256)
void thin70_k(const float* __restrict__ cur,
              const float* __restrict__ sub_w, const float* __restrict__ sub_b,
              const float* __restrict__ gate_w, const float* __restrict__ gate_b,
              const float* __restrict__ budget_w, const float* __restrict__ budget_b,
              float* __restrict__ S)
{
  int idx = blockIdx.x*256 + threadIdx.x;
  if (idx >= NI*70) return;
  int item = idx / 70, o = idx - item*70;
  const float* wp; float bb2;
  if (o < 60){ wp = sub_w + (size_t)o*DIM; bb2 = sub_b[o]; }
  else if (o < 65){ wp = gate_w + (size_t)(o-60)*DIM; bb2 = gate_b[o-60]; }
  else { wp = budget_w + (size_t)(o-65)*DIM; bb2 = budget_b[o-65]; }
  S[(size_t)item*72 + o] = dot256f(cur + (size_t)item*DIM, wp, 0.f) + bb2;
}

// --------------- router stage 2: per-item softmax + top-k ------------------
__global__ __launch_bounds__(256)
void topk_k(const float* __restrict__ S, float* __restrict__ sparse)
{
  int item = blockIdx.x*256 + threadIdx.x;
  if (item >= NI) return;
  const float* Si = S + (size_t)item*72;
  float probs[NEXPERT_];
  #pragma unroll
  for (int e = 0; e < NEXPERT_; e++) probs[e] = 0.f;
  float g[5];
  float gm = -1e30f;
  #pragma unroll
  for (int s = 0; s < 5; s++){ g[s] = Si[60+s]; gm = fmaxf(gm, g[s]); }
  float gs = 0.f;
  #pragma unroll
  for (int s = 0; s < 5; s++){ g[s] = __expf(g[s]-gm); gs += g[s]; }
  float gi = 1.f/gs;
  #pragma unroll
  for (int s = 0; s < 5; s++){
    float sl[NEXPERT_];
    float mx = -1e30f;
    #pragma unroll
    for (int e = 0; e < NEXPERT_; e++){ sl[e] = Si[s*NEXPERT_ + e]; mx = fmaxf(mx, sl[e]); }
    float se = 0.f;
    #pragma unroll
    for (int e = 0; e < NEXPERT_; e++){ sl[e] = __expf(sl[e]-mx); se += sl[e]; }
    float w2 = g[s]*gi/se;
    #pragma unroll
    for (int e = 0; e < NEXPERT_; e++) probs[e] = fmaf(w2, sl[e], probs[e]);
  }
  float bl0 = Si[65];
  int am = 0;
  #pragma unroll
  for (int s = 1; s < 5; s++){ float bv = Si[65+s]; if (bv > bl0){ bl0 = bv; am = s; } }
  int kact = am + 1;
  unsigned used = 0;
  float tv[5]; int ti[5];
  float ssum = 0.f;
  #pragma unroll
  for (int j = 0; j < 5; j++){
    float bv = -1e30f; int bi = 0;
    #pragma unroll
    for (int e = 0; e < NEXPERT_; e++){
      bool ok = !((used >> e) & 1u);
      if (ok && probs[e] > bv){ bv = probs[e]; bi = e; }
    }
    used |= (1u << bi);
    tv[j] = bv; ti[j] = bi;
    if (j < kact) ssum += bv;
  }
  float den = 1.f/fmaxf(ssum, 1e-6f);
  #pragma unroll
  for (int e = 0; e < NEXPERT_; e++){
    float v = 0.f;
    #pragma unroll
    for (int j = 0; j < 5; j++) if (j < kact && ti[j] == e) v = tv[j];
    sparse[(size_t)item*NEXPERT_ + e] = v*den;
  }
}

// -------- router stage 3: per-expert gather list (LDS compaction) ----------
__global__ __launch_bounds__(256)
void buildlist_k(const float* __restrict__ sparse, int* __restrict__ idxl,
                 int* __restrict__ cnt)
{
  __shared__ int lcnt;
  int e = blockIdx.x;
  if (threadIdx.x == 0) lcnt = 0;
  __syncthreads();
  for (int item = threadIdx.x; item < NI; item += 256){
    if (sparse[(size_t)item*NEXPERT_ + e] != 0.f){
      int s = atomicAdd(&lcnt, 1);
      idxl[(size_t)e*NI + s] = item;
    }
  }
  __syncthreads();
  if (threadIdx.x == 0) cnt[e] = lcnt;
}

// ---------------- 10-dim heads (reflect/coll/ver/corr/base) ----------------
__global__ __launch_bounds__(256)
void heads_k(const float* __restrict__ rbuf, const float* __restrict__ coll_ctx,
             const float* __restrict__ ver_ctx, const float* __restrict__ vbuf,
             const float* __restrict__ x,
             const float* __restrict__ reflect_out_w, const float* __restrict__ coll_out_w,
             const float* __restrict__ ver_out_w, const float* __restrict__ correction_out_w,
             const float* __restrict__ Wm, const float* __restrict__ bvec,
             float* __restrict__ reflect10, float* __restrict__ coll10,
             float* __restrict__ ver10, float* __restrict__ corr10,
             float* __restrict__ base10)
{
  int idx = blockIdx.x*256 + threadIdx.x;
  if (idx >= NI*50) return;
  int which = idx / (NI*ODIM), rem = idx - which*NI*ODIM;
  int item = rem / ODIM, o = rem - item*ODIM;
  const float* A; const float* Wp; float* C; float b2 = 0.f;
  if      (which == 0){ A = rbuf;     Wp = reflect_out_w;    C = reflect10; }
  else if (which == 1){ A = coll_ctx; Wp = coll_out_w;       C = coll10; }
  else if (which == 2){ A = ver_ctx;  Wp = ver_out_w;        C = ver10; }
  else if (which == 3){ A = vbuf;     Wp = correction_out_w; C = corr10; }
  else               { A = x;        Wp = Wm;               C = base10; b2 = bvec[o]; }
  float s = dot256f(A + (size_t)item*DIM, Wp + (size_t)o*DIM, 0.f) + b2;
  C[(size_t)item*ODIM + o] = s;
}

// ------------------------------ final combine ------------------------------
__global__ void final_k(
  const float* __restrict__ x, const float* __restrict__ cur,
  const float* __restrict__ vbuf, const float* __restrict__ coll_ctx,
  const float* __restrict__ ver_ctx,
  const float* __restrict__ base10, const float* __restrict__ shared_pre,
  const float* __restrict__ aux_pre, const float* __restrict__ expert_pre,
  const float* __restrict__ sparse, const float* __restrict__ mem_logits,
  const float* __restrict__ depth_logits, const float* __restrict__ reflect10,
  const float* __restrict__ coll10, const float* __restrict__ ver10,
  const float* __restrict__ corr10,
  const float* __restrict__ shared_ln_s, const float* __restrict__ shared_ln_b,
  const float* __restrict__ aux_ln_s, const float* __restrict__ aux_ln_b,
  const float* __restrict__ exp_ln_s, const float* __restrict__ exp_ln_b,
  const float* __restrict__ aux_gate_w, const float* __restrict__ aux_gate_b,
  const float* __restrict__ ver_gate_w, const float* __restrict__ ver_gate_b,
  const float* __restrict__ revisit_w, const float* __restrict__ revisit_b,
  const float* __restrict__ shared_scale, const float* __restrict__ mix,
  float* __restrict__ out)
{
  int item = blockIdx.x*256 + threadIdx.x;
  if (item >= NI) return;
  const float* xr = x + (size_t)item*DIM;
  const float* cr = cur + (size_t)item*DIM;
  const float* vr = vbuf + (size_t)item*DIM;
  const float* lr = coll_ctx + (size_t)item*DIM;
  const float* tr = ver_ctx + (size_t)item*DIM;
  float ag0 = aux_gate_b[0], ag1 = aux_gate_b[1];
  for (int k = 0; k < DIM; k++){
    float xv = xr[k];
    ag0 = fmaf(xv, aux_gate_w[k], ag0);
    ag1 = fmaf(xv, aux_gate_w[DIM+k], ag1);
  }
  { float m = fmaxf(ag0,ag1); float e0 = __expf(ag0-m), e1 = __expf(ag1-m);
    float i2 = 1.f/(e0+e1); ag0 = e0*i2; ag1 = e1*i2; }
  float vg0 = ver_gate_b[0], vg1 = ver_gate_b[1];
  for (int k = 0; k < DIM; k++){
    vg0 = fmaf(vr[k], ver_gate_w[k], vg0);
    vg1 = fmaf(vr[k], ver_gate_w[512+k], vg1);
  }
  for (int k = 0; k < DIM; k++){
    vg0 = fmaf(tr[k], ver_gate_w[DIM+k], vg0);
    vg1 = fmaf(tr[k], ver_gate_w[512+DIM+k], vg1);
  }
  { float m = fmaxf(vg0,vg1); float e0 = __expf(vg0-m), e1 = __expf(vg1-m);
    float i2 = 1.f/(e0+e1); vg0 = e0*i2; vg1 = e1*i2; }
  float rv = revisit_b[0];
  for (int k = 0; k < DIM; k++){
    rv = fmaf(xr[k], revisit_w[k], rv);
    rv = fmaf(cr[k], revisit_w[DIM+k], rv);
    rv = fmaf(lr[k], revisit_w[2*DIM+k], rv);
  }
  rv = sigm(rv);
  float sh[ODIM], axl[ODIM];
  { float tmp[ODIM];
    #pragma unroll
    for (int o = 0; o < ODIM; o++) tmp[o] = shared_pre[(size_t)item*ODIM + o];
    ln10(tmp, shared_ln_s, shared_ln_b, sh);
    #pragma unroll
    for (int o = 0; o < ODIM; o++) tmp[o] = aux_pre[(size_t)item*ODIM + o];
    ln10(tmp, aux_ln_s, aux_ln_b, axl); }
  float eo[ODIM];
  #pragma unroll
  for (int o = 0; o < ODIM; o++) eo[o] = 0.f;
  for (int i2 = 0; i2 < NEXPERT_; i2++){
    float sp = sparse[(size_t)item*NEXPERT_ + i2];
    if (sp != 0.f){
      float tmp[ODIM], lo[ODIM];
      #pragma unroll
      for (int o = 0; o < ODIM; o++) tmp[o] = expert_pre[((size_t)i2*NI + item)*ODIM + o];
      ln10(tmp, exp_ln_s + i2*ODIM, exp_ln_b + i2*ODIM, lo);
      #pragma unroll
      for (int o = 0; o < ODIM; o++) eo[o] = fmaf(sp, lo[o], eo[o]);
    }
  }
  float al = tanh_f(mix[0]), be = tanh_f(mix[1]), ga = tanh_f(mix[2]);
  float de = tanh_f(mix[3]), ep = tanh_f(mix[4]), ze = tanh_f(mix[5]);
  float ss = shared_scale[0];
  #pragma unroll
  for (int o = 0; o < ODIM; o++){
    size_t ix = (size_t)item*ODIM + o;
    float v = base10[ix]
      + ss*(ag0*sh[o] + ag1*axl[o])
      + al*eo[o]
      + be*mem_logits[ix] + ze*depth_logits[ix]
      + ga*reflect10[ix]
      + de*rv*coll10[ix]
      + ep*(vg0*ver10[ix] + vg1*corr10[ix]);
    out[ix] = v;
  }
}

// ------------------------------- host side ---------------------------------

static void launch_cvt(const float* in, unsigned short* out, size_t n, hipStream_t stream)
{
  cvt_k<<<(unsigned)((n/4 + 255)/256), 256, 0, stream>>>(in, out, (int)n);
}

extern "C" void kernel_launch(void* const* d_in, const int* in_sizes, int n_in,
                              void* d_out, int out_size, void* d_ws, size_t ws_size,
                              hipStream_t stream)
{
  (void)in_sizes; (void)n_in; (void)out_size; (void)ws_size;
  const float* x             = (const float*)d_in[0];
  const float* Wm            = (const float*)d_in[1];
  const float* bvec          = (const float*)d_in[2];
  const float* shared_up_w   = (const float*)d_in[3];
  const float* shared_down_w = (const float*)d_in[4];
  const float* shared_ln_s   = (const float*)d_in[5];
  const float* shared_ln_b   = (const float*)d_in[6];
  const float* shared_scale  = (const float*)d_in[7];
  const float* mem_keys      = (const float*)d_in[8];
  const float* mem_vals      = (const float*)d_in[9];
  const float* mem_q_w       = (const float*)d_in[10];
  const float* mem_out_w     = (const float*)d_in[11];
  const float* mem_wg_w      = (const float*)d_in[12];
  const float* mem_wg_b      = (const float*)d_in[13];
  const float* mem_wv_w      = (const float*)d_in[14];
  const float* mem_wv_b      = (const float*)d_in[15];
  const float* depth_q_w     = (const float*)d_in[16];
  const float* depth_k_w     = (const float*)d_in[17];
  const float* depth_v_w     = (const float*)d_in[18];
  const float* depth_out_w   = (const float*)d_in[19];
  const float* rc_ln_s       = (const float*)d_in[20];
  const float* rc_ln_b       = (const float*)d_in[21];
  const float* rc_w1         = (const float*)d_in[22];
  const float* rc_b1         = (const float*)d_in[23];
  const float* rc_w2         = (const float*)d_in[24];
  const float* rc_b2         = (const float*)d_in[25];
  const float* ssm_in_w      = (const float*)d_in[26];
  const float* ssm_out_w     = (const float*)d_in[27];
  const float* ssm_decay     = (const float*)d_in[28];
  const float* sub_w         = (const float*)d_in[29];
  const float* sub_b         = (const float*)d_in[30];
  const float* gate_w        = (const float*)d_in[31];
  const float* gate_b        = (const float*)d_in[32];
  const float* budget_w      = (const float*)d_in[33];
  const float* budget_b      = (const float*)d_in[34];
  const float* halt_w        = (const float*)d_in[35];
  const float* halt_b        = (const float*)d_in[36];
  const float* aux_up_w      = (const float*)d_in[37];
  const float* aux_down_w    = (const float*)d_in[38];
  const float* aux_ln_s      = (const float*)d_in[39];
  const float* aux_ln_b      = (const float*)d_in[40];
  const float* aux_gate_w    = (const float*)d_in[41];
  const float* aux_gate_b    = (const float*)d_in[42];
  const float* rf_ln_s       = (const float*)d_in[43];
  const float* rf_ln_b       = (const float*)d_in[44];
  const float* rf_w1         = (const float*)d_in[45];
  const float* rf_b1         = (const float*)d_in[46];
  const float* rf_w2         = (const float*)d_in[47];
  const float* rf_b2         = (const float*)d_in[48];
  const float* reflect_out_w = (const float*)d_in[49];
  const float* coll_q_w      = (const float*)d_in[50];
  const float* coll_k_w      = (const float*)d_in[51];
  const float* coll_v_w      = (const float*)d_in[52];
  const float* coll_out_w    = (const float*)d_in[53];
  const float* revisit_w     = (const float*)d_in[54];
  const float* revisit_b     = (const float*)d_in[55];
  const float* vc_ln_s       = (const float*)d_in[56];
  const float* vc_ln_b       = (const float*)d_in[57];
  const float* vc_w1         = (const float*)d_in[58];
  const float* vc_b1         = (const float*)d_in[59];
  const float* vc_w2         = (const float*)d_in[60];
  const float* vc_b2         = (const float*)d_in[61];
  const float* ver_q_w       = (const float*)d_in[62];
  const float* ver_k_w       = (const float*)d_in[63];
  const float* ver_v_w       = (const float*)d_in[64];
  const float* ver_out_w     = (const float*)d_in[65];
  const float* ver_gate_w    = (const float*)d_in[66];
  const float* ver_gate_b    = (const float*)d_in[67];
  const float* correction_out_w = (const float*)d_in[68];
  const float* mix           = (const float*)d_in[69];
  const float* exp_up        = (const float*)d_in[70];
  const float* exp_down      = (const float*)d_in[71];
  const float* exp_ln_s      = (const float*)d_in[72];
  const float* exp_ln_b      = (const float*)d_in[73];
  float* out = (float*)d_out;

  // ---- workspace: persistent region ----
  float* w = (float*)d_ws;
  size_t off = 0;
  auto WS = [&](size_t nf){ float* p = w + off; off += nf; return p; };
  float* bank      = WS((size_t)NSTEPS_*NI*DIM);
  float* rbuf      = WS((size_t)NI*DIM);
  float* vbuf      = WS((size_t)NI*DIM);
  float* coll_ctx  = WS((size_t)NI*DIM);
  float* ver_ctx   = WS((size_t)NI*DIM);
  float* q2        = WS((size_t)NI*DIM);
  float* wsumb     = WS((size_t)NI*DIM);
  float* sparse    = WS((size_t)NI*NEXPERT_);
  float* base10    = WS((size_t)NI*ODIM);
  float* reflect10 = WS((size_t)NI*ODIM);
  float* coll10    = WS((size_t)NI*ODIM);
  float* ver10     = WS((size_t)NI*ODIM);
  float* corr10    = WS((size_t)NI*ODIM);
  float* PcT       = WS((size_t)DIM*DIM);
  float* PvT       = WS((size_t)DIM*DIM);
  float* MK        = WS((size_t)NMEM_*DIM);
  float* Wvq       = WS((size_t)512*DIM);          // [mem_wv_w ; PdT]
  float* expert_pre= WS((size_t)NEXPERT_*NI*ODIM);
  float* shared_pre= WS((size_t)NI*ODIM);
  float* aux_pre   = WS((size_t)NI*ODIM);
  unsigned short* cur_b = (unsigned short*)WS((size_t)NI*DIM/2);
  unsigned short* x_b   = (unsigned short*)WS((size_t)NI*DIM/2);
  int* idxl        = (int*)WS((size_t)NEXPERT_*NI);
  float* S72       = WS((size_t)NI*72);
  int* cnt         = (int*)WS(16);
  // zero-initialized accumulators
  float* zbase     = w + off;
  float* mem_logits   = WS((size_t)NI*ODIM);
  float* depth_logits = WS((size_t)NI*ODIM);
  float* cum_halt     = WS((size_t)NI);
  size_t zbytes = (size_t)((w + off) - zbase) * sizeof(float);
  hipMemsetAsync((void*)zbase, 0, zbytes, stream);

  // ---- union region: loop scratch, overlaid post-loop ----
  float* U = w + off;
  float* wv_hist   = U;
  float* hbig      = U + (size_t)NSTEPS_*NI*DIM;
  float* cur_in    = hbig + (size_t)NI*896;
  float* t_ln      = cur_in + (size_t)NI*DIM;
  float* mem_read  = t_ln + (size_t)NI*DIM;
  float* depth_ctx = mem_read + (size_t)NI*DIM;
  float* a_state   = depth_ctx + (size_t)NI*DIM;
  float* c_state   = a_state + (size_t)NI*NMEM_;
  // post-loop overlay inside U:
  unsigned short* upb    = (unsigned short*)U;
  unsigned short* hb     = (unsigned short*)U;     // aliases upb (used after moe)
  float* ovl = U + 5963776;
  unsigned short* t_ln_b = (unsigned short*)ovl;          ovl += 524288;
  unsigned short* rfw1b  = (unsigned short*)ovl;          ovl += 491520;
  unsigned short* rfw2b  = (unsigned short*)ovl;          ovl += 491520;
  unsigned short* vcw1b  = (unsigned short*)ovl;          ovl += 393216;
  unsigned short* vcw2b  = (unsigned short*)ovl;          ovl += 393216;
  unsigned short* part   = (unsigned short*)ovl;

  // ---- precompute: collapsed attention matrices + combined wv|Pd weight ----
  hipMemcpyAsync(Wvq, mem_wv_w, (size_t)DIM*DIM*sizeof(float),
                 hipMemcpyDeviceToDevice, stream);
  atb_k<<<(DIM*DIM+255)/256, 256, 0, stream>>>(depth_k_w, depth_q_w, Wvq + (size_t)DIM*DIM, DIM, DIM, DIM);
  atb_k<<<(DIM*DIM+255)/256, 256, 0, stream>>>(coll_k_w,  coll_q_w,  PcT, DIM, DIM, DIM);
  atb_k<<<(DIM*DIM+255)/256, 256, 0, stream>>>(ver_k_w,   ver_q_w,   PvT, DIM, DIM, DIM);
  ab_k <<<(NMEM_*DIM+255)/256, 256, 0, stream>>>(mem_keys, mem_q_w, MK, NMEM_, DIM, DIM);

  // ---- recurrent loop (fp32) ----
  const float* cur = x;
  for (int s = 0; s < NSTEPS_; s++){
    memrw_k<<<NI/4, 256, 0, stream>>>(cur, MK, mem_vals, wv_hist,
                                      mem_wg_w, mem_wg_b, a_state, c_state,
                                      mem_read, s);
    if (s == 0){
      gemm_k<1><<<dim3(4, NI/64), 256, 0, stream>>>(
          cur, Wvq, mem_wv_b, nullptr, wv_hist, nullptr, DIM, DIM);
    } else if (s == NSTEPS_-1){
      gemm_k<0><<<dim3(4, NI/64), 256, 0, stream>>>(
          cur, Wvq + (size_t)DIM*DIM, nullptr, nullptr, q2, nullptr, DIM, DIM);
    } else {
      gemm_k<6><<<dim3(8, NI/64), 256, 0, stream>>>(
          cur, Wvq, mem_wv_b, nullptr, wv_hist + (size_t)s*NI*DIM, q2, 512, DIM);
    }
    if (s > 0){
      bankattn_k<<<NI/4, 256, 0, stream>>>(q2, bank, wsumb, s);
      gemm_k<0><<<dim3(4, NI/64), 256, 0, stream>>>(
          wsumb, depth_v_w, nullptr, nullptr, depth_ctx, nullptr, DIM, DIM);
    }
    ln3_k<<<NI/4, 256, 0, stream>>>(cur, mem_read, (s > 0 ? depth_ctx : nullptr),
                                    rc_ln_s + (size_t)s*DIM, rc_ln_b + (size_t)s*DIM,
                                    cur_in, t_ln, nullptr);
    gemm_rc1_k<<<dim3(14, NI/128), 256, 0, stream>>>(
        t_ln, rc_w1 + (size_t)s*896*DIM, rc_b1 + (size_t)s*896, hbig, 896, DIM);
    gemm_k<3><<<dim3(4, NI/64), 256, 0, stream>>>(
        hbig, rc_w2 + (size_t)s*DIM*896, rc_b2 + (size_t)s*DIM, cur_in,
        cur_in, nullptr, DIM, 896);
    float* newcur = bank + (size_t)s*NI*DIM;
    ssmhalt_k<<<NI/4, 256, 0, stream>>>(cur_in, mem_read, depth_ctx,
                                        ssm_in_w, ssm_out_w, ssm_decay,
                                        halt_w, halt_b, mem_out_w, depth_out_w,
                                        newcur, mem_logits, depth_logits, cum_halt, s);
    cur = newcur;
  }

  // ---- router: projections -> top-k -> gather lists ----
  thin70_k<<<(NI*70 + 255)/256, 256, 0, stream>>>(
      cur, sub_w, sub_b, gate_w, gate_b, budget_w, budget_b, S72);
  topk_k<<<(NI + 255)/256, 256, 0, stream>>>(S72, sparse);
  buildlist_k<<<NEXPERT_, 256, 0, stream>>>(sparse, idxl, cnt);

  // ---- post-loop conversions into overlay (loop scratch now dead) ----
  launch_cvt(cur, cur_b, (size_t)NI*DIM, stream);
  launch_cvt(x,   x_b,   (size_t)NI*DIM, stream);
  cvtup_k<<<TOTCOL/64, 512, 0, stream>>>(exp_up, shared_up_w, aux_up_w, (short*)upb);
  launch_cvt(rf_w1, rfw1b, (size_t)3*1280*DIM, stream);
  launch_cvt(rf_w2, rfw2b, (size_t)3*DIM*1280, stream);
  launch_cvt(vc_w1, vcw1b, (size_t)2*1536*DIM, stream);
  launch_cvt(vc_w2, vcw2b, (size_t)2*DIM*1536, stream);

  // ---- experts (gathered) + shared + aux (dense): ONE launch, no LDS ----
  moe8_k<<<dim3(NI/128, 182), 512, 0, stream>>>(
      cur_b, x_b, (const short*)upb, exp_down, shared_down_w, aux_down_w,
      idxl, cnt, part);
  red_k<<<(14*NI*ODIM + 255)/256, 256, 0, stream>>>(part, expert_pre, shared_pre, aux_pre);

  // ---- reflection (3 cells, 1280, bf16 MFMA) ----
  const float* rsrc = cur;
  for (int i = 0; i < 3; i++){
    ln3_k<<<NI/4, 256, 0, stream>>>(rsrc, nullptr, nullptr,
                                    rf_ln_s + (size_t)i*DIM, rf_ln_b + (size_t)i*DIM,
                                    nullptr, nullptr, t_ln_b);
    bgemm_k<0><<<dim3(1280/64, NI/128), 256, 0, stream>>>(
        (const short*)t_ln_b, (const short*)(rfw1b + (size_t)i*1280*DIM),
        rf_b1 + (size_t)i*1280, nullptr, nullptr, hb, 1280, DIM);
    bgemm_k<1><<<dim3(DIM/64, NI/128), 256, 0, stream>>>(
        (const short*)hb, (const short*)(rfw2b + (size_t)i*DIM*1280),
        rf_b2 + (size_t)i*DIM, rsrc, rbuf, nullptr, DIM, 1280);
    rsrc = rbuf;
  }

  // ---- verifier (2 cells, 1536, bf16 MFMA) ----
  const float* vsrc = cur;
  for (int i = 0; i < 2; i++){
    ln3_k<<<NI/4, 256, 0, stream>>>(vsrc, nullptr, nullptr,
                                    vc_ln_s + (size_t)i*DIM, vc_ln_b + (size_t)i*DIM,
                                    nullptr, nullptr, t_ln_b);
    bgemm_k<0><<<dim3(1536/64, NI/128), 256, 0, stream>>>(
        (const short*)t_ln_b, (const short*)(vcw1b + (size_t)i*1536*DIM),
        vc_b1 + (size_t)i*1536, nullptr, nullptr, hb, 1536, DIM);
    bgemm_k<1><<<dim3(DIM/64, NI/128), 256, 0, stream>>>(
        (const short*)hb, (const short*)(vcw2b + (size_t)i*DIM*1536),
        vc_b2 + (size_t)i*DIM, vsrc, vbuf, nullptr, DIM, 1536);
    vsrc = vbuf;
  }

  // ---- collective attention over bank ----
  gemm_k<0><<<dim3(4, NI/64), 256, 0, stream>>>(
      cur, PcT, nullptr, nullptr, q2, nullptr, DIM, DIM);
  bankattn_k<<<NI/4, 256, 0, stream>>>(q2, bank, wsumb, NSTEPS_);
  gemm_k<0><<<dim3(4, NI/64), 256, 0, stream>>>(
      wsumb, coll_v_w, nullptr, nullptr, coll_ctx, nullptr, DIM, DIM);

  // ---- verifier attention over bank ----
  gemm_k<0><<<dim3(4, NI/64), 256, 0, stream>>>(
      vbuf, PvT, nullptr, nullptr, q2, nullptr, DIM, DIM);
  bankattn_k<<<NI/4, 256, 0, stream>>>(q2, bank, wsumb, NSTEPS_);
  gemm_k<0><<<dim3(4, NI/64), 256, 0, stream>>>(
      wsumb, ver_v_w, nullptr, nullptr, ver_ctx, nullptr, DIM, DIM);

  // ---- 10-dim heads (incl. base) ----
  heads_k<<<(NI*50 + 255)/256, 256, 0, stream>>>(
      rbuf, coll_ctx, ver_ctx, vbuf, x,
      reflect_out_w, coll_out_w, ver_out_w, correction_out_w, Wm, bvec,
      reflect10, coll10, ver10, corr10, base10);

  // ---- final combine ----
  final_k<<<(NI+255)/256, 256, 0, stream>>>(
      x, cur, vbuf, coll_ctx, ver_ctx,
      base10, shared_pre, aux_pre, expert_pre, sparse,
      mem_logits, depth_logits, reflect10, coll10, ver10, corr10,
      shared_ln_s, shared_ln_b, aux_ln_s, aux_ln_b, exp_ln_s, exp_ln_b,
      aux_gate_w, aux_gate_b, ver_gate_w, ver_gate_b, revisit_w, revisit_b,
      shared_scale, mix, out);
}

// Round 12
// 2767.607 us; speedup vs baseline: 1.1087x; 1.1087x over previous
//
#include <hip/hip_runtime.h>

// ---------------------------------------------------------------------------
// FrontierVerifierExpertHead — round 12 = round 10 exactly (proven best,
// 2770 us). moe7_k single-launch LDS pipeline; ln3+gemm_rc1 loop; split
// router; gemm6 trims at s=0/s=5.
// ---------------------------------------------------------------------------

constexpr int NI      = 4096;
constexpr int DIM     = 256;
constexpr int ODIM    = 10;
constexpr int NMEM_   = 32;
constexpr int NSTEPS_ = 6;
constexpr int NEXPERT_= 12;
constexpr int MAXE    = 4608;
constexpr int TOTCOL  = 46592;  // 12 experts tight + shared 3072 + aux 4096
#define SCL 0.0625f             // 256^-0.5

__constant__ int GCNT[14]   = {8,10,12,14,16,9,11,13,15,18,12,16,12,16};
__constant__ int GSTART[14] = {0,8,18,30,44,60,69,80,93,108,126,138,154,166};
__constant__ int CCNT[14]   = {32,40,48,56,64,36,44,52,60,72,48,64,48,64};
__constant__ int ZCOL[14]   = {0,2048,4608,7680,11264,15360,17664,20480,
                               23808,27648,32256,35328,39424,42496};

typedef __attribute__((ext_vector_type(8))) short short8v;
typedef __attribute__((ext_vector_type(4))) float float4v;
typedef __attribute__((ext_vector_type(4))) unsigned short ushort4v;

// ----------------------------- device helpers ------------------------------

__device__ __forceinline__ float wred_sum(float v){
  #pragma unroll
  for (int m = 32; m > 0; m >>= 1) v += __shfl_xor(v, m, 64);
  return v;
}
__device__ __forceinline__ float wred_max(float v){
  #pragma unroll
  for (int m = 32; m > 0; m >>= 1) v = fmaxf(v, __shfl_xor(v, m, 64));
  return v;
}
// ---- fast inline transcendentals (no OCML calls) ----
__device__ __forceinline__ float sigm(float x){ return 1.f/(1.f + __expf(-x)); }
__device__ __forceinline__ float tanh_f(float x){
  float e = __expf(2.f*fabsf(x));
  float r = 1.f - 2.f/(e + 1.f);
  return copysignf(r, x);
}
__device__ __forceinline__ float erf_f(float x){
  float ax = fabsf(x);
  float t = 1.f/fmaf(0.3275911f, ax, 1.f);
  float p = t*(0.254829592f + t*(-0.284496736f + t*(1.421413741f +
            t*(-1.453152027f + t*1.061405429f))));
  float r = 1.f - p*__expf(-ax*ax);
  return copysignf(r, x);
}
__device__ __forceinline__ float geluf(float x){
  return 0.5f*x*(1.f + erf_f(x*0.70710678118654752f));
}
__device__ __forceinline__ float softplusf(float x){
  return fmaxf(x, 0.f) + __logf(1.f + __expf(-fabsf(x)));
}
__device__ __forceinline__ unsigned short f2b(float f){   // fp32 -> bf16 RNE
  unsigned u = __float_as_uint(f);
  u = u + 0x7FFFu + ((u >> 16) & 1u);
  return (unsigned short)(u >> 16);
}
__device__ __forceinline__ float b2f(unsigned short u){
  return __uint_as_float((unsigned)u << 16);
}
__device__ __forceinline__ float dot256f(const float* __restrict__ a,
                                         const float* __restrict__ w, float s){
  for (int k = 0; k < DIM; k += 4){
    float4 av = *(const float4*)&a[k];
    float4 wv = *(const float4*)&w[k];
    s = fmaf(av.x,wv.x, fmaf(av.y,wv.y, fmaf(av.z,wv.z, fmaf(av.w,wv.w, s))));
  }
  return s;
}
__device__ __forceinline__ void ln10(const float* p, const float* s, const float* b, float* o){
  float mu = 0.f;
  #pragma unroll
  for (int i=0;i<ODIM;i++) mu += p[i];
  mu *= 0.1f;
  float var = 0.f;
  #pragma unroll
  for (int i=0;i<ODIM;i++){ float d = p[i]-mu; var += d*d; }
  var *= 0.1f;
  float rs = 1.f/sqrtf(var + 1e-5f);
  #pragma unroll
  for (int i=0;i<ODIM;i++) o[i] = (p[i]-mu)*rs*s[i] + b[i];
}

// ------------------------- fp32 -> bf16 converter --------------------------
__global__ __launch_bounds__(256)
void cvt_k(const float* __restrict__ in, unsigned short* __restrict__ out, int n)
{
  int idx = (blockIdx.x*256 + threadIdx.x)*4;
  if (idx + 3 < n){
    float4 v = *(const float4*)&in[idx];
    ushort4v t; t[0]=f2b(v.x); t[1]=f2b(v.y); t[2]=f2b(v.z); t[3]=f2b(v.w);
    *(ushort4v*)&out[idx] = t;
  }
}

// ----------------- up-weight convert to tight kq-major bf16 ----------------
__global__ __launch_bounds__(512)
void cvtup_k(const float* __restrict__ exp_up, const float* __restrict__ shared_up,
             const float* __restrict__ aux_up, short* __restrict__ upb)
{
  int chunk = blockIdx.x;
  int z = 0, crem = chunk;
  while (crem >= CCNT[z]){ crem -= CCNT[z]; z++; }
  const float* src;
  if (z < 12)       src = exp_up + (size_t)z*MAXE*DIM;
  else if (z == 12) src = shared_up;
  else              src = aux_up;
  int colbase = crem*64;
  short* dst = upb + (size_t)chunk*16384;
  int t = threadIdx.x;
  int c = t >> 3, kb = (t & 7)*32;
  const float* srow = src + (size_t)(colbase + c)*DIM + kb;
  #pragma unroll
  for (int j = 0; j < 4; j++){
    float4 f0 = *(const float4*)&srow[j*8];
    float4 f1 = *(const float4*)&srow[j*8+4];
    short8v s;
    s[0]=(short)f2b(f0.x); s[1]=(short)f2b(f0.y); s[2]=(short)f2b(f0.z); s[3]=(short)f2b(f0.w);
    s[4]=(short)f2b(f1.x); s[5]=(short)f2b(f1.y); s[6]=(short)f2b(f1.z); s[7]=(short)f2b(f1.w);
    int kq = (t & 7)*4 + j;
    *(short8v*)&dst[((size_t)kq*64 + c)*8] = s;
  }
}

// ----------------------------- tiled fp32 GEMM (64x64) ---------------------
// EPI: 0 none | 1 +bias | 3 +bias+R | 6 split col<256 -> C(+bias) else C2
template<int EPI>
__global__ __launch_bounds__(256)
void gemm_k(const float* __restrict__ A, const float* __restrict__ W,
            const float* __restrict__ bias, const float* __restrict__ R,
            float* __restrict__ C, float* __restrict__ C2, int N, int K)
{
  __shared__ float As[32][68];
  __shared__ float Ws[32][68];
  const int bm = blockIdx.y*64, bn = blockIdx.x*64;
  const int tid = threadIdx.x;
  const int tx = tid & 15, ty = tid >> 4;
  const int lrow = tid >> 2, lkq = (tid & 3) * 8;
  float acc[4][4] = {};
  for (int k0 = 0; k0 < K; k0 += 32){
    #pragma unroll
    for (int h = 0; h < 2; ++h){
      int kk = lkq + h*4;
      float4 va = *(const float4*)&A[(size_t)(bm+lrow)*K + k0 + kk];
      float4 vw = *(const float4*)&W[(size_t)(bn+lrow)*K + k0 + kk];
      As[kk+0][lrow]=va.x; As[kk+1][lrow]=va.y; As[kk+2][lrow]=va.z; As[kk+3][lrow]=va.w;
      Ws[kk+0][lrow]=vw.x; Ws[kk+1][lrow]=vw.y; Ws[kk+2][lrow]=vw.z; Ws[kk+3][lrow]=vw.w;
    }
    __syncthreads();
    #pragma unroll
    for (int kk = 0; kk < 32; ++kk){
      float4 a4 = *(const float4*)&As[kk][ty*4];
      float4 b4 = *(const float4*)&Ws[kk][tx*4];
      float av[4] = {a4.x,a4.y,a4.z,a4.w};
      float bv[4] = {b4.x,b4.y,b4.z,b4.w};
      #pragma unroll
      for (int i=0;i<4;i++)
        #pragma unroll
        for (int j=0;j<4;j++) acc[i][j] = fmaf(av[i], bv[j], acc[i][j]);
    }
    __syncthreads();
  }
  #pragma unroll
  for (int i=0;i<4;i++){
    int r = bm + ty*4 + i;
    #pragma unroll
    for (int j=0;j<4;j++){
      int c = bn + tx*4 + j;
      float v = acc[i][j];
      if constexpr (EPI==0){ C[(size_t)r*N + c] = v; }
      else if constexpr (EPI==1){ C[(size_t)r*N + c] = v + bias[c]; }
      else if constexpr (EPI==3){ C[(size_t)r*N + c] = v + bias[c] + R[(size_t)r*N + c]; }
      else if constexpr (EPI==6){
        if (c < 256) C[(size_t)r*256 + c] = v + bias[c];
        else C2[(size_t)r*256 + (c-256)] = v;
      }
    }
  }
}

// ------------------- fp32 128x64 tile GEMM, gelu epilogue ------------------
__global__ __launch_bounds__(256)
void gemm_rc1_k(const float* __restrict__ A, const float* __restrict__ W,
                const float* __restrict__ bias, float* __restrict__ C,
                int N, int K)
{
  __shared__ float As[32][132];
  __shared__ float Ws[32][68];
  const int bm = blockIdx.y*128, bn = blockIdx.x*64;
  const int tid = threadIdx.x;
  const int tx = tid & 15, ty = tid >> 4;
  const int arow = tid >> 1, ak = (tid & 1)*16;
  const int brow = tid >> 2, bk = (tid & 3)*8;
  float acc[8][4] = {};
  for (int k0 = 0; k0 < K; k0 += 32){
    float4 a0 = *(const float4*)&A[(size_t)(bm+arow)*K + k0 + ak];
    float4 a1 = *(const float4*)&A[(size_t)(bm+arow)*K + k0 + ak + 4];
    float4 a2 = *(const float4*)&A[(size_t)(bm+arow)*K + k0 + ak + 8];
    float4 a3 = *(const float4*)&A[(size_t)(bm+arow)*K + k0 + ak + 12];
    float4 b0 = *(const float4*)&W[(size_t)(bn+brow)*K + k0 + bk];
    float4 b1 = *(const float4*)&W[(size_t)(bn+brow)*K + k0 + bk + 4];
    As[ak+ 0][arow]=a0.x; As[ak+ 1][arow]=a0.y; As[ak+ 2][arow]=a0.z; As[ak+ 3][arow]=a0.w;
    As[ak+ 4][arow]=a1.x; As[ak+ 5][arow]=a1.y; As[ak+ 6][arow]=a1.z; As[ak+ 7][arow]=a1.w;
    As[ak+ 8][arow]=a2.x; As[ak+ 9][arow]=a2.y; As[ak+10][arow]=a2.z; As[ak+11][arow]=a2.w;
    As[ak+12][arow]=a3.x; As[ak+13][arow]=a3.y; As[ak+14][arow]=a3.z; As[ak+15][arow]=a3.w;
    Ws[bk+0][brow]=b0.x; Ws[bk+1][brow]=b0.y; Ws[bk+2][brow]=b0.z; Ws[bk+3][brow]=b0.w;
    Ws[bk+4][brow]=b1.x; Ws[bk+5][brow]=b1.y; Ws[bk+6][brow]=b1.z; Ws[bk+7][brow]=b1.w;
    __syncthreads();
    #pragma unroll
    for (int kk = 0; kk < 32; ++kk){
      float a8[8];
      *(float4*)&a8[0] = *(const float4*)&As[kk][ty*8];
      *(float4*)&a8[4] = *(const float4*)&As[kk][ty*8+4];
      float4 b4 = *(const float4*)&Ws[kk][tx*4];
      float bv[4] = {b4.x,b4.y,b4.z,b4.w};
      #pragma unroll
      for (int i=0;i<8;i++)
        #pragma unroll
        for (int j=0;j<4;j++) acc[i][j] = fmaf(a8[i], bv[j], acc[i][j]);
    }
    __syncthreads();
  }
  #pragma unroll
  for (int i=0;i<8;i++){
    int r = bm + ty*8 + i;
    #pragma unroll
    for (int j=0;j<4;j++){
      int c = bn + tx*4 + j;
      C[(size_t)r*N + c] = geluf(acc[i][j] + bias[c]);
    }
  }
}

// ------------------------------ bf16 MFMA GEMM -----------------------------
// EPI 0: gelu(acc+bias) -> bf16 Cb ; EPI 1: acc+bias+R -> f32 Cf
template<int EPI>
__global__ __launch_bounds__(256)
void bgemm_k(const short* __restrict__ A, const short* __restrict__ B,
             const float* __restrict__ bias, const float* __restrict__ R,
             float* __restrict__ Cf, unsigned short* __restrict__ Cb,
             int N, int K)
{
  __shared__ short As[128][40];
  __shared__ short Bsm[64][40];
  const int bm = blockIdx.y*128, bn = blockIdx.x*64;
  const int tid = threadIdx.x;
  const int wave = tid >> 6, lane = tid & 63;
  const int l15 = lane & 15, lg = lane >> 4;
  const int ar = tid >> 1, ah = tid & 1;
  float4v acc[2][4] = {};
  for (int k0 = 0; k0 < K; k0 += 32){
    __syncthreads();
    { const short* src = A + (size_t)(bm+ar)*K + k0 + ah*16;
      short8v v0 = *(const short8v*)src;
      short8v v1 = *(const short8v*)(src+8);
      *(short8v*)&As[ar][ah*16]   = v0;
      *(short8v*)&As[ar][ah*16+8] = v1; }
    if (tid < 128){
      const short* src = B + (size_t)(bn+ar)*K + k0 + ah*16;
      short8v v0 = *(const short8v*)src;
      short8v v1 = *(const short8v*)(src+8);
      *(short8v*)&Bsm[ar][ah*16]   = v0;
      *(short8v*)&Bsm[ar][ah*16+8] = v1; }
    __syncthreads();
    short8v bfr[4];
    #pragma unroll
    for (int nt = 0; nt < 4; nt++)
      bfr[nt] = *(const short8v*)&Bsm[nt*16 + l15][lg*8];
    #pragma unroll
    for (int mt = 0; mt < 2; mt++){
      short8v a = *(const short8v*)&As[wave*32 + mt*16 + l15][lg*8];
      #pragma unroll
      for (int nt = 0; nt < 4; nt++)
        acc[mt][nt] = __builtin_amdgcn_mfma_f32_16x16x32_bf16(a, bfr[nt], acc[mt][nt], 0, 0, 0);
    }
  }
  #pragma unroll
  for (int mt = 0; mt < 2; mt++)
    #pragma unroll
    for (int nt = 0; nt < 4; nt++)
      #pragma unroll
      for (int reg = 0; reg < 4; reg++){
        int row = bm + wave*32 + mt*16 + lg*4 + reg;
        int col = bn + nt*16 + l15;
        float v = acc[mt][nt][reg];
        if constexpr (EPI==0){
          v = geluf(v + bias[col]);
          Cb[(size_t)row*N + col] = f2b(v);
        } else {
          v = v + bias[col] + R[(size_t)row*N + col];
          Cf[(size_t)row*N + col] = v;
        }
      }
}

// ---- fused MoE (gathered) / shared / aux (dense), SINGLE LAUNCH, MFMA -----
__global__ __launch_bounds__(512)
void moe7_k(const unsigned short* __restrict__ curb, const unsigned short* __restrict__ xb,
            const short* __restrict__ upb,
            const float* __restrict__ exp_down, const float* __restrict__ shared_down,
            const float* __restrict__ aux_down,
            const int* __restrict__ idxl, const int* __restrict__ cnt,
            unsigned short* __restrict__ part)
{
  __shared__ short Bs[16384];
  __shared__ float Ds[64][12];
  int gy = blockIdx.y, z = 0;
  while (gy >= GCNT[z]){ gy -= GCNT[z]; z++; }
  const int n = (z < 12) ? cnt[z] : NI;
  const int bm = blockIdx.x*128;
  if (bm >= n) return;
  const int g = GSTART[z] + gy;
  const int localcol = gy*256;
  int act, dstride; const float* down;
  if (z < 12){ act = z & 7; down = exp_down + (size_t)z*ODIM*MAXE; dstride = MAXE; }
  else if (z == 12){ act = 0; down = shared_down; dstride = 3072; }
  else { act = 1; down = aux_down; dstride = 4096; }
  const unsigned short* X = (z < 12) ? curb : xb;
  const int tid = threadIdx.x, wave = tid >> 6, lane = tid & 63;
  const int l15 = lane & 15, lg = lane >> 4;

  int slotA = bm + wave*16 + l15;
  int itemA;
  if (z < 12) itemA = idxl[(size_t)z*NI + ((slotA < n) ? slotA : (n-1))];
  else        itemA = slotA;

  short8v afrag[8];
  { const unsigned short* xr = X + (size_t)itemA*DIM;
    #pragma unroll
    for (int ks = 0; ks < 8; ks++)
      afrag[ks] = *(const short8v*)&xr[ks*32 + lg*8];
  }
  float racc[4][10];
  #pragma unroll
  for (int r = 0; r < 4; r++)
    #pragma unroll
    for (int o = 0; o < 10; o++) racc[r][o] = 0.f;

  const int gchunk0 = (ZCOL[z] + localcol) >> 6;
  const int dso = tid >> 6, dse = tid & 63;

  // named-register staging state (no arrays -> no scratch)
  short8v p0, p1, p2, p3;
  float e0, e1;
  auto ldchunk = [&](int ch){
    const short* chunk = upb + ((size_t)(gchunk0 + ch))*16384;
    p0 = *(const short8v*)&chunk[(size_t)(tid       )*8];
    p1 = *(const short8v*)&chunk[(size_t)(tid +  512)*8];
    p2 = *(const short8v*)&chunk[(size_t)(tid + 1024)*8];
    p3 = *(const short8v*)&chunk[(size_t)(tid + 1536)*8];
    int cb = localcol + ch*64;
    e0 = down[(size_t)dso*dstride + cb + dse];
    e1 = (tid < 128) ? down[(size_t)(dso+8)*dstride + cb + dse] : 0.f;
  };
  auto stu = [&](int u, short8v v){
    int c = u & 63, kq = u >> 6;
    int byteoff = ((c << 9) + (kq << 4)) ^ ((c & 7) << 4);
    *(short8v*)((char*)Bs + byteoff) = v;
  };

  ldchunk(0);
  for (int ch = 0; ch < 4; ++ch){
    stu(tid, p0); stu(tid + 512, p1); stu(tid + 1024, p2); stu(tid + 1536, p3);
    Ds[dse][dso] = e0;
    if (tid < 128) Ds[dse][dso + 8] = e1;
    __syncthreads();
    if (ch < 3) ldchunk(ch + 1);     // prefetch overlaps MFMA below
    float4v acc[4] = {};
    #pragma unroll
    for (int ks = 0; ks < 8; ks++)
      #pragma unroll
      for (int nt = 0; nt < 4; nt++){
        int c = nt*16 + l15, kq = ks*4 + lg;
        int byteoff = ((c << 9) + (kq << 4)) ^ ((c & 7) << 4);
        short8v b = *(const short8v*)((const char*)Bs + byteoff);
        acc[nt] = __builtin_amdgcn_mfma_f32_16x16x32_bf16(afrag[ks], b, acc[nt], 0, 0, 0);
      }
    // activation: ONE uniform runtime switch, unrolled bodies (static idx only)
    float hv[4][4];
    switch(act){
      case 0:
        #pragma unroll
        for (int nt=0;nt<4;nt++)
          #pragma unroll
          for (int r=0;r<4;r++){ float xx=acc[nt][r]; hv[nt][r]=xx*sigm(xx); }
        break;
      case 1:
        #pragma unroll
        for (int nt=0;nt<4;nt++)
          #pragma unroll
          for (int r=0;r<4;r++){ hv[nt][r]=geluf(acc[nt][r]); }
        break;
      case 2:
        #pragma unroll
        for (int nt=0;nt<4;nt++)
          #pragma unroll
          for (int r=0;r<4;r++){ float xx=acc[nt][r]; hv[nt][r]=xx*tanh_f(softplusf(xx)); }
        break;
      case 3:
        #pragma unroll
        for (int nt=0;nt<4;nt++)
          #pragma unroll
          for (int r=0;r<4;r++){ hv[nt][r]=fmaxf(acc[nt][r],0.f); }
        break;
      case 4:
        #pragma unroll
        for (int nt=0;nt<4;nt++)
          #pragma unroll
          for (int r=0;r<4;r++){
            const float l=1.0507009873554805f, al=1.6732632423543772f;
            float xx=acc[nt][r];
            hv[nt][r] = xx>0.f ? l*xx : l*al*(__expf(xx)-1.f);
          }
        break;
      case 5:
        #pragma unroll
        for (int nt=0;nt<4;nt++)
          #pragma unroll
          for (int r=0;r<4;r++){ hv[nt][r]=tanh_f(acc[nt][r]); }
        break;
      case 6:
        #pragma unroll
        for (int nt=0;nt<4;nt++)
          #pragma unroll
          for (int r=0;r<4;r++){ hv[nt][r]=softplusf(acc[nt][r]); }
        break;
      default:
        #pragma unroll
        for (int nt=0;nt<4;nt++)
          #pragma unroll
          for (int r=0;r<4;r++){ float xx=acc[nt][r]; hv[nt][r]= xx>0.f ? xx : __expf(xx)-1.f; }
        break;
    }
    #pragma unroll
    for (int nt = 0; nt < 4; nt++){
      const float* dp = &Ds[nt*16 + l15][0];
      float4 dv0 = *(const float4*)dp;
      float4 dv1 = *(const float4*)(dp + 4);
      float  d8 = dp[8], d9 = dp[9];
      float dv[10] = {dv0.x,dv0.y,dv0.z,dv0.w,dv1.x,dv1.y,dv1.z,dv1.w,d8,d9};
      #pragma unroll
      for (int o = 0; o < 10; o++)
        #pragma unroll
        for (int r = 0; r < 4; r++)
          racc[r][o] = fmaf(hv[nt][r], dv[o], racc[r][o]);
    }
    __syncthreads();
  }
  #pragma unroll
  for (int r = 0; r < 4; r++)
    #pragma unroll
    for (int o = 0; o < 10; o++){
      float v = racc[r][o];
      v += __shfl_xor(v, 1, 64); v += __shfl_xor(v, 2, 64);
      v += __shfl_xor(v, 4, 64); v += __shfl_xor(v, 8, 64);
      racc[r][o] = v;
    }
  if (l15 == 0){
    #pragma unroll
    for (int r = 0; r < 4; r++){
      int slotW = bm + wave*16 + lg*4 + r;
      int itemW;
      if (z < 12) itemW = idxl[(size_t)z*NI + ((slotW < n) ? slotW : (n-1))];
      else        itemW = slotW;
      #pragma unroll
      for (int o = 0; o < 10; o++)
        part[((size_t)g*NI + itemW)*ODIM + o] = f2b(racc[r][o]);
    }
  }
}

// --------------------------- partials reduce 182 -> 14 ---------------------
__global__ __launch_bounds__(256)
void red_k(const unsigned short* __restrict__ part, float* __restrict__ expert_pre,
           float* __restrict__ shared_pre, float* __restrict__ aux_pre)
{
  int idx = blockIdx.x*256 + threadIdx.x;
  if (idx >= 14*NI*ODIM) return;
  int z = idx / (NI*ODIM), rem = idx - z*NI*ODIM;
  float s = 0.f;
  int g0 = GSTART[z], gn = GCNT[z];
  for (int g2 = 0; g2 < gn; g2++)
    s += b2f(part[(size_t)(g0 + g2)*NI*ODIM + rem]);
  if (z < 12) expert_pre[(size_t)z*NI*ODIM + rem] = s;
  else if (z == 12) shared_pre[rem] = s;
  else aux_pre[rem] = s;
}

// ----------------------- small one-off matrix products ---------------------
__global__ void atb_k(const float* __restrict__ A, const float* __restrict__ B,
                      float* __restrict__ C, int M, int I, int J)
{
  int idx = blockIdx.x*256 + threadIdx.x;
  if (idx >= I*J) return;
  int i = idx / J, j = idx - i*J;
  float s = 0.f;
  for (int m = 0; m < M; m++) s = fmaf(A[(size_t)m*I+i], B[(size_t)m*J+j], s);
  C[idx] = s;
}
__global__ void ab_k(const float* __restrict__ A, const float* __restrict__ B,
                     float* __restrict__ C, int M, int K, int N)
{
  int idx = blockIdx.x*256 + threadIdx.x;
  if (idx >= M*N) return;
  int i = idx / N, j = idx - i*N;
  float s = 0.f;
  for (int k = 0; k < K; k++) s = fmaf(A[(size_t)i*K+k], B[(size_t)k*N+j], s);
  C[idx] = s;
}

// --------------------- LN (+up to 2 extra addends), D=256 ------------------
__global__ __launch_bounds__(256)
void ln3_k(const float* __restrict__ a, const float* __restrict__ b,
           const float* __restrict__ c, const float* __restrict__ lns,
           const float* __restrict__ lnb, float* __restrict__ xout,
           float* __restrict__ lnout, unsigned short* __restrict__ lnout_b)
{
  int item = blockIdx.x*4 + (threadIdx.x >> 6);
  int lane = threadIdx.x & 63;
  float4 v = ((const float4*)(a + (size_t)item*DIM))[lane];
  if (b){ float4 t = ((const float4*)(b + (size_t)item*DIM))[lane]; v.x+=t.x; v.y+=t.y; v.z+=t.z; v.w+=t.w; }
  if (c){ float4 t = ((const float4*)(c + (size_t)item*DIM))[lane]; v.x+=t.x; v.y+=t.y; v.z+=t.z; v.w+=t.w; }
  if (xout) ((float4*)(xout + (size_t)item*DIM))[lane] = v;
  float mu = wred_sum(v.x+v.y+v.z+v.w) * (1.f/DIM);
  float dx=v.x-mu, dy=v.y-mu, dz=v.z-mu, dw=v.w-mu;
  float var = wred_sum(dx*dx+dy*dy+dz*dz+dw*dw) * (1.f/DIM);
  float rs = 1.f/sqrtf(var + 1e-5f);
  float4 s4 = ((const float4*)lns)[lane];
  float4 b4 = ((const float4*)lnb)[lane];
  float4 o4 = make_float4(dx*rs*s4.x + b4.x, dy*rs*s4.y + b4.y,
                          dz*rs*s4.z + b4.z, dw*rs*s4.w + b4.w);
  if (lnout) ((float4*)(lnout + (size_t)item*DIM))[lane] = o4;
  if (lnout_b){
    ushort4v t; t[0]=f2b(o4.x); t[1]=f2b(o4.y); t[2]=f2b(o4.z); t[3]=f2b(o4.w);
    *(ushort4v*)(lnout_b + (size_t)item*DIM + lane*4) = t;
  }
}

// ----- memory read + softmax + factorized bank read + write-gate update ----
__global__ __launch_bounds__(256)
void memrw_k(const float* __restrict__ cur, const float* __restrict__ MK,
             const float* __restrict__ mem_vals, const float* __restrict__ wv_hist,
             const float* __restrict__ mem_wg_w, const float* __restrict__ mem_wg_b,
             float* __restrict__ a_state, float* __restrict__ c_state,
             float* __restrict__ mem_read, int step)
{
  __shared__ float smem[4][DIM];
  int wi = threadIdx.x >> 6;
  int item = blockIdx.x*4 + wi;
  int lane = threadIdx.x & 63;
  float v = -1e30f;
  if (lane < NMEM_)
    v = dot256f(cur + (size_t)item*DIM, MK + (size_t)lane*DIM, 0.f) * SCL;
  float m = wred_max(v);
  float e = (lane < NMEM_) ? __expf(v - m) : 0.f;
  float inv = 1.f / wred_sum(e);
  float attn = e * inv;
  float aval = 0.f;
  if (lane < NMEM_) aval = (step == 0) ? 1.f : a_state[(size_t)item*NMEM_ + lane];
  float wslot = attn * aval;
  float beta[NSTEPS_];
  #pragma unroll
  for (int t = 0; t < NSTEPS_; t++){
    beta[t] = 0.f;
    if (t < step){
      float cc = (lane < NMEM_) ? c_state[((size_t)item*NMEM_ + lane)*NSTEPS_ + t] : 0.f;
      beta[t] = wred_sum(attn * cc);
    }
  }
  float ax=0.f, ay=0.f, az=0.f, aw=0.f;
  #pragma unroll
  for (int s2 = 0; s2 < NMEM_; s2++){
    float ws = __shfl(wslot, s2, 64);
    float4 mv = ((const float4*)(mem_vals + (size_t)s2*DIM))[lane];
    ax = fmaf(ws, mv.x, ax); ay = fmaf(ws, mv.y, ay);
    az = fmaf(ws, mv.z, az); aw = fmaf(ws, mv.w, aw);
  }
  #pragma unroll
  for (int t = 0; t < NSTEPS_; t++){
    if (t < step){
      float4 h4 = ((const float4*)(wv_hist + ((size_t)t*NI + item)*DIM))[lane];
      ax = fmaf(beta[t], h4.x, ax); ay = fmaf(beta[t], h4.y, ay);
      az = fmaf(beta[t], h4.z, az); aw = fmaf(beta[t], h4.w, aw);
    }
  }
  float4 mr = make_float4(ax,ay,az,aw);
  ((float4*)(mem_read + (size_t)item*DIM))[lane] = mr;
  ((float4*)&smem[wi][0])[lane] = mr;
  __syncthreads();
  if (lane < NMEM_){
    const float* wr = mem_wg_w + (size_t)lane*2*DIM;
    float s = dot256f(cur + (size_t)item*DIM, wr, 0.f);
    s = dot256f(&smem[wi][0], wr + DIM, s);
    s += mem_wg_b[lane];
    float gte = sigm(s);
    int idx = item*NMEM_ + lane;
    float om = 1.f - gte;
    float a = (step == 0) ? 1.f : a_state[idx];
    a_state[idx] = a * om;
    float* c = c_state + (size_t)idx*NSTEPS_;
    #pragma unroll
    for (int t = 0; t < NSTEPS_; t++) if (t < step) c[t] *= om;
    c[step] = gte;
  }
}

// ------------------- bank attention (scores+softmax+wsum) ------------------
__global__ __launch_bounds__(256)
void bankattn_k(const float* __restrict__ q2, const float* __restrict__ bank,
                float* __restrict__ wsum, int t)
{
  int item = blockIdx.x*4 + (threadIdx.x >> 6);
  int lane = threadIdx.x & 63;
  float4 q4 = ((const float4*)(q2 + (size_t)item*DIM))[lane];
  float sc[NSTEPS_];
  float4 bb[NSTEPS_];
  #pragma unroll
  for (int j = 0; j < NSTEPS_; j++){
    if (j < t){
      bb[j] = ((const float4*)(bank + ((size_t)j*NI + item)*DIM))[lane];
      sc[j] = wred_sum(q4.x*bb[j].x + q4.y*bb[j].y + q4.z*bb[j].z + q4.w*bb[j].w) * SCL;
    }
  }
  float mx = -1e30f;
  #pragma unroll
  for (int j = 0; j < NSTEPS_; j++) if (j < t) mx = fmaxf(mx, sc[j]);
  float se = 0.f;
  #pragma unroll
  for (int j = 0; j < NSTEPS_; j++) if (j < t){ sc[j] = __expf(sc[j]-mx); se += sc[j]; }
  float inv = 1.f/se;
  float ax=0.f, ay=0.f, az=0.f, aw=0.f;
  #pragma unroll
  for (int j = 0; j < NSTEPS_; j++){
    if (j < t){
      float a = sc[j]*inv;
      ax = fmaf(a, bb[j].x, ax); ay = fmaf(a, bb[j].y, ay);
      az = fmaf(a, bb[j].z, az); aw = fmaf(a, bb[j].w, aw);
    }
  }
  ((float4*)(wsum + (size_t)item*DIM))[lane] = make_float4(ax,ay,az,aw);
}

// -------- SSM adapter + halting-weighted logits (one wave per item) --------
__global__ __launch_bounds__(256)
void ssmhalt_k(const float* __restrict__ cur_in, const float* __restrict__ mem_read,
               const float* __restrict__ depth_ctx,
               const float* __restrict__ ssm_in_w, const float* __restrict__ ssm_out_w,
               const float* __restrict__ ssm_decay,
               const float* __restrict__ halt_w, const float* __restrict__ halt_b,
               const float* __restrict__ mem_out_w, const float* __restrict__ depth_out_w,
               float* __restrict__ newcur, float* __restrict__ mem_logits,
               float* __restrict__ depth_logits, float* __restrict__ cum_halt, int step)
{
  __shared__ float sh48[4][48];
  int wi = threadIdx.x >> 6;
  int item = blockIdx.x*4 + wi;
  int lane = threadIdx.x & 63;
  const float* ci = cur_in + (size_t)item*DIM;
  if (lane < 48){
    float s = dot256f(ci, ssm_in_w + (size_t)lane*DIM, 0.f);
    sh48[wi][lane] = tanh_f(s) * sigm(ssm_decay[lane]);
  }
  __syncthreads();
  float4 nc = ((const float4*)ci)[lane];
  float o0 = nc.x, o1 = nc.y, o2 = nc.z, o3 = nc.w;
  const float* so = ssm_out_w + (size_t)(lane*4)*48;
  #pragma unroll 8
  for (int j = 0; j < 48; j++){
    float h = sh48[wi][j];
    o0 = fmaf(h, so[j],       o0);
    o1 = fmaf(h, so[48 + j],  o1);
    o2 = fmaf(h, so[96 + j],  o2);
    o3 = fmaf(h, so[144 + j], o3);
  }
  ((float4*)(newcur + (size_t)item*DIM))[lane] = make_float4(o0,o1,o2,o3);
  float4 hw = ((const float4*)(halt_w + (size_t)step*DIM))[lane];
  float hd = wred_sum(o0*hw.x + o1*hw.y + o2*hw.z + o3*hw.w);
  float halt = sigm(hd + halt_b[step]);
  float ch = cum_halt[item];
  float wstep = (1.f - ch) * halt;
  float4 m4 = ((const float4*)(mem_read + (size_t)item*DIM))[lane];
  float4 d4 = make_float4(0.f,0.f,0.f,0.f);
  if (step > 0) d4 = ((const float4*)(depth_ctx + (size_t)item*DIM))[lane];
  #pragma unroll
  for (int o = 0; o < ODIM; o++){
    float4 w4 = ((const float4*)(mem_out_w + (size_t)o*DIM))[lane];
    float s = wred_sum(m4.x*w4.x + m4.y*w4.y + m4.z*w4.z + m4.w*w4.w);
    if (lane == 0) mem_logits[(size_t)item*ODIM + o] += wstep * s;
    if (step > 0){
      float4 v4 = ((const float4*)(depth_out_w + (size_t)o*DIM))[lane];
      float s2 = wred_sum(d4.x*v4.x + d4.y*v4.y + d4.z*v4.z + d4.w*v4.w);
      if (lane == 0) depth_logits[(size_t)item*ODIM + o] += wstep * s2;
    }
  }
  if (lane == 0) cum_halt[item] = fminf(ch + halt, 1.f);
}

// --------------- router stage 1: 70 projections (flat, parallel) -----------
__global__ __launch_bounds__(256)
void thin70_k(const float* __restrict__ cur,
              const float* __restrict__ sub_w, const float* __restrict__ sub_b,
              const float* __restrict__ gate_w, const float* __restrict__ gate_b,
              const float* __restrict__ budget_w, const float* __restrict__ budget_b,
              float* __restrict__ S)
{
  int idx = blockIdx.x*256 + threadIdx.x;
  if (idx >= NI*70) return;
  int item = idx / 70, o = idx - item*70;
  const float* wp; float bb2;
  if (o < 60){ wp = sub_w + (size_t)o*DIM; bb2 = sub_b[o]; }
  else if (o < 65){ wp = gate_w + (size_t)(o-60)*DIM; bb2 = gate_b[o-60]; }
  else { wp = budget_w + (size_t)(o-65)*DIM; bb2 = budget_b[o-65]; }
  S[(size_t)item*72 + o] = dot256f(cur + (size_t)item*DIM, wp, 0.f) + bb2;
}

// --------------- router stage 2: per-item softmax + top-k ------------------
__global__ __launch_bounds__(256)
void topk_k(const float* __restrict__ S, float* __restrict__ sparse)
{
  int item = blockIdx.x*256 + threadIdx.x;
  if (item >= NI) return;
  const float* Si = S + (size_t)item*72;
  float probs[NEXPERT_];
  #pragma unroll
  for (int e = 0; e < NEXPERT_; e++) probs[e] = 0.f;
  float g[5];
  float gm = -1e30f;
  #pragma unroll
  for (int s = 0; s < 5; s++){ g[s] = Si[60+s]; gm = fmaxf(gm, g[s]); }
  float gs = 0.f;
  #pragma unroll
  for (int s = 0; s < 5; s++){ g[s] = __expf(g[s]-gm); gs += g[s]; }
  float gi = 1.f/gs;
  #pragma unroll
  for (int s = 0; s < 5; s++){
    float sl[NEXPERT_];
    float mx = -1e30f;
    #pragma unroll
    for (int e = 0; e < NEXPERT_; e++){ sl[e] = Si[s*NEXPERT_ + e]; mx = fmaxf(mx, sl[e]); }
    float se = 0.f;
    #pragma unroll
    for (int e = 0; e < NEXPERT_; e++){ sl[e] = __expf(sl[e]-mx); se += sl[e]; }
    float w2 = g[s]*gi/se;
    #pragma unroll
    for (int e = 0; e < NEXPERT_; e++) probs[e] = fmaf(w2, sl[e], probs[e]);
  }
  float bl0 = Si[65];
  int am = 0;
  #pragma unroll
  for (int s = 1; s < 5; s++){ float bv = Si[65+s]; if (bv > bl0){ bl0 = bv; am = s; } }
  int kact = am + 1;
  unsigned used = 0;
  float tv[5]; int ti[5];
  float ssum = 0.f;
  #pragma unroll
  for (int j = 0; j < 5; j++){
    float bv = -1e30f; int bi = 0;
    #pragma unroll
    for (int e = 0; e < NEXPERT_; e++){
      bool ok = !((used >> e) & 1u);
      if (ok && probs[e] > bv){ bv = probs[e]; bi = e; }
    }
    used |= (1u << bi);
    tv[j] = bv; ti[j] = bi;
    if (j < kact) ssum += bv;
  }
  float den = 1.f/fmaxf(ssum, 1e-6f);
  #pragma unroll
  for (int e = 0; e < NEXPERT_; e++){
    float v = 0.f;
    #pragma unroll
    for (int j = 0; j < 5; j++) if (j < kact && ti[j] == e) v = tv[j];
    sparse[(size_t)item*NEXPERT_ + e] = v*den;
  }
}

// -------- router stage 3: per-expert gather list (LDS compaction) ----------
__global__ __launch_bounds__(256)
void buildlist_k(const float* __restrict__ sparse, int* __restrict__ idxl,
                 int* __restrict__ cnt)
{
  __shared__ int lcnt;
  int e = blockIdx.x;
  if (threadIdx.x == 0) lcnt = 0;
  __syncthreads();
  for (int item = threadIdx.x; item < NI; item += 256){
    if (sparse[(size_t)item*NEXPERT_ + e] != 0.f){
      int s = atomicAdd(&lcnt, 1);
      idxl[(size_t)e*NI + s] = item;
    }
  }
  __syncthreads();
  if (threadIdx.x == 0) cnt[e] = lcnt;
}

// ---------------- 10-dim heads (reflect/coll/ver/corr/base) ----------------
__global__ __launch_bounds__(256)
void heads_k(const float* __restrict__ rbuf, const float* __restrict__ coll_ctx,
             const float* __restrict__ ver_ctx, const float* __restrict__ vbuf,
             const float* __restrict__ x,
             const float* __restrict__ reflect_out_w, const float* __restrict__ coll_out_w,
             const float* __restrict__ ver_out_w, const float* __restrict__ correction_out_w,
             const float* __restrict__ Wm, const float* __restrict__ bvec,
             float* __restrict__ reflect10, float* __restrict__ coll10,
             float* __restrict__ ver10, float* __restrict__ corr10,
             float* __restrict__ base10)
{
  int idx = blockIdx.x*256 + threadIdx.x;
  if (idx >= NI*50) return;
  int which = idx / (NI*ODIM), rem = idx - which*NI*ODIM;
  int item = rem / ODIM, o = rem - item*ODIM;
  const float* A; const float* Wp; float* C; float b2 = 0.f;
  if      (which == 0){ A = rbuf;     Wp = reflect_out_w;    C = reflect10; }
  else if (which == 1){ A = coll_ctx; Wp = coll_out_w;       C = coll10; }
  else if (which == 2){ A = ver_ctx;  Wp = ver_out_w;        C = ver10; }
  else if (which == 3){ A = vbuf;     Wp = correction_out_w; C = corr10; }
  else               { A = x;        Wp = Wm;               C = base10; b2 = bvec[o]; }
  float s = dot256f(A + (size_t)item*DIM, Wp + (size_t)o*DIM, 0.f) + b2;
  C[(size_t)item*ODIM + o] = s;
}

// ------------------------------ final combine ------------------------------
__global__ void final_k(
  const float* __restrict__ x, const float* __restrict__ cur,
  const float* __restrict__ vbuf, const float* __restrict__ coll_ctx,
  const float* __restrict__ ver_ctx,
  const float* __restrict__ base10, const float* __restrict__ shared_pre,
  const float* __restrict__ aux_pre, const float* __restrict__ expert_pre,
  const float* __restrict__ sparse, const float* __restrict__ mem_logits,
  const float* __restrict__ depth_logits, const float* __restrict__ reflect10,
  const float* __restrict__ coll10, const float* __restrict__ ver10,
  const float* __restrict__ corr10,
  const float* __restrict__ shared_ln_s, const float* __restrict__ shared_ln_b,
  const float* __restrict__ aux_ln_s, const float* __restrict__ aux_ln_b,
  const float* __restrict__ exp_ln_s, const float* __restrict__ exp_ln_b,
  const float* __restrict__ aux_gate_w, const float* __restrict__ aux_gate_b,
  const float* __restrict__ ver_gate_w, const float* __restrict__ ver_gate_b,
  const float* __restrict__ revisit_w, const float* __restrict__ revisit_b,
  const float* __restrict__ shared_scale, const float* __restrict__ mix,
  float* __restrict__ out)
{
  int item = blockIdx.x*256 + threadIdx.x;
  if (item >= NI) return;
  const float* xr = x + (size_t)item*DIM;
  const float* cr = cur + (size_t)item*DIM;
  const float* vr = vbuf + (size_t)item*DIM;
  const float* lr = coll_ctx + (size_t)item*DIM;
  const float* tr = ver_ctx + (size_t)item*DIM;
  float ag0 = aux_gate_b[0], ag1 = aux_gate_b[1];
  for (int k = 0; k < DIM; k++){
    float xv = xr[k];
    ag0 = fmaf(xv, aux_gate_w[k], ag0);
    ag1 = fmaf(xv, aux_gate_w[DIM+k], ag1);
  }
  { float m = fmaxf(ag0,ag1); float e0 = __expf(ag0-m), e1 = __expf(ag1-m);
    float i2 = 1.f/(e0+e1); ag0 = e0*i2; ag1 = e1*i2; }
  float vg0 = ver_gate_b[0], vg1 = ver_gate_b[1];
  for (int k = 0; k < DIM; k++){
    vg0 = fmaf(vr[k], ver_gate_w[k], vg0);
    vg1 = fmaf(vr[k], ver_gate_w[512+k], vg1);
  }
  for (int k = 0; k < DIM; k++){
    vg0 = fmaf(tr[k], ver_gate_w[DIM+k], vg0);
    vg1 = fmaf(tr[k], ver_gate_w[512+DIM+k], vg1);
  }
  { float m = fmaxf(vg0,vg1); float e0 = __expf(vg0-m), e1 = __expf(vg1-m);
    float i2 = 1.f/(e0+e1); vg0 = e0*i2; vg1 = e1*i2; }
  float rv = revisit_b[0];
  for (int k = 0; k < DIM; k++){
    rv = fmaf(xr[k], revisit_w[k], rv);
    rv = fmaf(cr[k], revisit_w[DIM+k], rv);
    rv = fmaf(lr[k], revisit_w[2*DIM+k], rv);
  }
  rv = sigm(rv);
  float sh[ODIM], axl[ODIM];
  { float tmp[ODIM];
    #pragma unroll
    for (int o = 0; o < ODIM; o++) tmp[o] = shared_pre[(size_t)item*ODIM + o];
    ln10(tmp, shared_ln_s, shared_ln_b, sh);
    #pragma unroll
    for (int o = 0; o < ODIM; o++) tmp[o] = aux_pre[(size_t)item*ODIM + o];
    ln10(tmp, aux_ln_s, aux_ln_b, axl); }
  float eo[ODIM];
  #pragma unroll
  for (int o = 0; o < ODIM; o++) eo[o] = 0.f;
  for (int i2 = 0; i2 < NEXPERT_; i2++){
    float sp = sparse[(size_t)item*NEXPERT_ + i2];
    if (sp != 0.f){
      float tmp[ODIM], lo[ODIM];
      #pragma unroll
      for (int o = 0; o < ODIM; o++) tmp[o] = expert_pre[((size_t)i2*NI + item)*ODIM + o];
      ln10(tmp, exp_ln_s + i2*ODIM, exp_ln_b + i2*ODIM, lo);
      #pragma unroll
      for (int o = 0; o < ODIM; o++) eo[o] = fmaf(sp, lo[o], eo[o]);
    }
  }
  float al = tanh_f(mix[0]), be = tanh_f(mix[1]), ga = tanh_f(mix[2]);
  float de = tanh_f(mix[3]), ep = tanh_f(mix[4]), ze = tanh_f(mix[5]);
  float ss = shared_scale[0];
  #pragma unroll
  for (int o = 0; o < ODIM; o++){
    size_t ix = (size_t)item*ODIM + o;
    float v = base10[ix]
      + ss*(ag0*sh[o] + ag1*axl[o])
      + al*eo[o]
      + be*mem_logits[ix] + ze*depth_logits[ix]
      + ga*reflect10[ix]
      + de*rv*coll10[ix]
      + ep*(vg0*ver10[ix] + vg1*corr10[ix]);
    out[ix] = v;
  }
}

// ------------------------------- host side ---------------------------------

static void launch_cvt(const float* in, unsigned short* out, size_t n, hipStream_t stream)
{
  cvt_k<<<(unsigned)((n/4 + 255)/256), 256, 0, stream>>>(in, out, (int)n);
}

extern "C" void kernel_launch(void* const* d_in, const int* in_sizes, int n_in,
                              void* d_out, int out_size, void* d_ws, size_t ws_size,
                              hipStream_t stream)
{
  (void)in_sizes; (void)n_in; (void)out_size; (void)ws_size;
  const float* x             = (const float*)d_in[0];
  const float* Wm            = (const float*)d_in[1];
  const float* bvec          = (const float*)d_in[2];
  const float* shared_up_w   = (const float*)d_in[3];
  const float* shared_down_w = (const float*)d_in[4];
  const float* shared_ln_s   = (const float*)d_in[5];
  const float* shared_ln_b   = (const float*)d_in[6];
  const float* shared_scale  = (const float*)d_in[7];
  const float* mem_keys      = (const float*)d_in[8];
  const float* mem_vals      = (const float*)d_in[9];
  const float* mem_q_w       = (const float*)d_in[10];
  const float* mem_out_w     = (const float*)d_in[11];
  const float* mem_wg_w      = (const float*)d_in[12];
  const float* mem_wg_b      = (const float*)d_in[13];
  const float* mem_wv_w      = (const float*)d_in[14];
  const float* mem_wv_b      = (const float*)d_in[15];
  const float* depth_q_w     = (const float*)d_in[16];
  const float* depth_k_w     = (const float*)d_in[17];
  const float* depth_v_w     = (const float*)d_in[18];
  const float* depth_out_w   = (const float*)d_in[19];
  const float* rc_ln_s       = (const float*)d_in[20];
  const float* rc_ln_b       = (const float*)d_in[21];
  const float* rc_w1         = (const float*)d_in[22];
  const float* rc_b1         = (const float*)d_in[23];
  const float* rc_w2         = (const float*)d_in[24];
  const float* rc_b2         = (const float*)d_in[25];
  const float* ssm_in_w      = (const float*)d_in[26];
  const float* ssm_out_w     = (const float*)d_in[27];
  const float* ssm_decay     = (const float*)d_in[28];
  const float* sub_w         = (const float*)d_in[29];
  const float* sub_b         = (const float*)d_in[30];
  const float* gate_w        = (const float*)d_in[31];
  const float* gate_b        = (const float*)d_in[32];
  const float* budget_w      = (const float*)d_in[33];
  const float* budget_b      = (const float*)d_in[34];
  const float* halt_w        = (const float*)d_in[35];
  const float* halt_b        = (const float*)d_in[36];
  const float* aux_up_w      = (const float*)d_in[37];
  const float* aux_down_w    = (const float*)d_in[38];
  const float* aux_ln_s      = (const float*)d_in[39];
  const float* aux_ln_b      = (const float*)d_in[40];
  const float* aux_gate_w    = (const float*)d_in[41];
  const float* aux_gate_b    = (const float*)d_in[42];
  const float* rf_ln_s       = (const float*)d_in[43];
  const float* rf_ln_b       = (const float*)d_in[44];
  const float* rf_w1         = (const float*)d_in[45];
  const float* rf_b1         = (const float*)d_in[46];
  const float* rf_w2         = (const float*)d_in[47];
  const float* rf_b2         = (const float*)d_in[48];
  const float* reflect_out_w = (const float*)d_in[49];
  const float* coll_q_w      = (const float*)d_in[50];
  const float* coll_k_w      = (const float*)d_in[51];
  const float* coll_v_w      = (const float*)d_in[52];
  const float* coll_out_w    = (const float*)d_in[53];
  const float* revisit_w     = (const float*)d_in[54];
  const float* revisit_b     = (const float*)d_in[55];
  const float* vc_ln_s       = (const float*)d_in[56];
  const float* vc_ln_b       = (const float*)d_in[57];
  const float* vc_w1         = (const float*)d_in[58];
  const float* vc_b1         = (const float*)d_in[59];
  const float* vc_w2         = (const float*)d_in[60];
  const float* vc_b2         = (const float*)d_in[61];
  const float* ver_q_w       = (const float*)d_in[62];
  const float* ver_k_w       = (const float*)d_in[63];
  const float* ver_v_w       = (const float*)d_in[64];
  const float* ver_out_w     = (const float*)d_in[65];
  const float* ver_gate_w    = (const float*)d_in[66];
  const float* ver_gate_b    = (const float*)d_in[67];
  const float* correction_out_w = (const float*)d_in[68];
  const float* mix           = (const float*)d_in[69];
  const float* exp_up        = (const float*)d_in[70];
  const float* exp_down      = (const float*)d_in[71];
  const float* exp_ln_s      = (const float*)d_in[72];
  const float* exp_ln_b      = (const float*)d_in[73];
  float* out = (float*)d_out;

  // ---- workspace: persistent region ----
  float* w = (float*)d_ws;
  size_t off = 0;
  auto WS = [&](size_t nf){ float* p = w + off; off += nf; return p; };
  float* bank      = WS((size_t)NSTEPS_*NI*DIM);
  float* rbuf      = WS((size_t)NI*DIM);
  float* vbuf      = WS((size_t)NI*DIM);
  float* coll_ctx  = WS((size_t)NI*DIM);
  float* ver_ctx   = WS((size_t)NI*DIM);
  float* q2        = WS((size_t)NI*DIM);
  float* wsumb     = WS((size_t)NI*DIM);
  float* sparse    = WS((size_t)NI*NEXPERT_);
  float* base10    = WS((size_t)NI*ODIM);
  float* reflect10 = WS((size_t)NI*ODIM);
  float* coll10    = WS((size_t)NI*ODIM);
  float* ver10     = WS((size_t)NI*ODIM);
  float* corr10    = WS((size_t)NI*ODIM);
  float* PcT       = WS((size_t)DIM*DIM);
  float* PvT       = WS((size_t)DIM*DIM);
  float* MK        = WS((size_t)NMEM_*DIM);
  float* Wvq       = WS((size_t)512*DIM);          // [mem_wv_w ; PdT]
  float* expert_pre= WS((size_t)NEXPERT_*NI*ODIM);
  float* shared_pre= WS((size_t)NI*ODIM);
  float* aux_pre   = WS((size_t)NI*ODIM);
  unsigned short* cur_b = (unsigned short*)WS((size_t)NI*DIM/2);
  unsigned short* x_b   = (unsigned short*)WS((size_t)NI*DIM/2);
  int* idxl        = (int*)WS((size_t)NEXPERT_*NI);
  float* S72       = WS((size_t)NI*72);
  int* cnt         = (int*)WS(16);
  // zero-initialized accumulators
  float* zbase     = w + off;
  float* mem_logits   = WS((size_t)NI*ODIM);
  float* depth_logits = WS((size_t)NI*ODIM);
  float* cum_halt     = WS((size_t)NI);
  size_t zbytes = (size_t)((w + off) - zbase) * sizeof(float);
  hipMemsetAsync((void*)zbase, 0, zbytes, stream);

  // ---- union region: loop scratch, overlaid post-loop ----
  float* U = w + off;
  float* wv_hist   = U;
  float* hbig      = U + (size_t)NSTEPS_*NI*DIM;
  float* cur_in    = hbig + (size_t)NI*896;
  float* t_ln      = cur_in + (size_t)NI*DIM;
  float* mem_read  = t_ln + (size_t)NI*DIM;
  float* depth_ctx = mem_read + (size_t)NI*DIM;
  float* a_state   = depth_ctx + (size_t)NI*DIM;
  float* c_state   = a_state + (size_t)NI*NMEM_;
  // post-loop overlay inside U:
  unsigned short* upb    = (unsigned short*)U;
  unsigned short* hb     = (unsigned short*)U;     // aliases upb (used after moe)
  float* ovl = U + 5963776;
  unsigned short* t_ln_b = (unsigned short*)ovl;          ovl += 524288;
  unsigned short* rfw1b  = (unsigned short*)ovl;          ovl += 491520;
  unsigned short* rfw2b  = (unsigned short*)ovl;          ovl += 491520;
  unsigned short* vcw1b  = (unsigned short*)ovl;          ovl += 393216;
  unsigned short* vcw2b  = (unsigned short*)ovl;          ovl += 393216;
  unsigned short* part   = (unsigned short*)ovl;

  // ---- precompute: collapsed attention matrices + combined wv|Pd weight ----
  hipMemcpyAsync(Wvq, mem_wv_w, (size_t)DIM*DIM*sizeof(float),
                 hipMemcpyDeviceToDevice, stream);
  atb_k<<<(DIM*DIM+255)/256, 256, 0, stream>>>(depth_k_w, depth_q_w, Wvq + (size_t)DIM*DIM, DIM, DIM, DIM);
  atb_k<<<(DIM*DIM+255)/256, 256, 0, stream>>>(coll_k_w,  coll_q_w,  PcT, DIM, DIM, DIM);
  atb_k<<<(DIM*DIM+255)/256, 256, 0, stream>>>(ver_k_w,   ver_q_w,   PvT, DIM, DIM, DIM);
  ab_k <<<(NMEM_*DIM+255)/256, 256, 0, stream>>>(mem_keys, mem_q_w, MK, NMEM_, DIM, DIM);

  // ---- recurrent loop (fp32) ----
  const float* cur = x;
  for (int s = 0; s < NSTEPS_; s++){
    memrw_k<<<NI/4, 256, 0, stream>>>(cur, MK, mem_vals, wv_hist,
                                      mem_wg_w, mem_wg_b, a_state, c_state,
                                      mem_read, s);
    if (s == 0){
      gemm_k<1><<<dim3(4, NI/64), 256, 0, stream>>>(
          cur, Wvq, mem_wv_b, nullptr, wv_hist, nullptr, DIM, DIM);
    } else if (s == NSTEPS_-1){
      gemm_k<0><<<dim3(4, NI/64), 256, 0, stream>>>(
          cur, Wvq + (size_t)DIM*DIM, nullptr, nullptr, q2, nullptr, DIM, DIM);
    } else {
      gemm_k<6><<<dim3(8, NI/64), 256, 0, stream>>>(
          cur, Wvq, mem_wv_b, nullptr, wv_hist + (size_t)s*NI*DIM, q2, 512, DIM);
    }
    if (s > 0){
      bankattn_k<<<NI/4, 256, 0, stream>>>(q2, bank, wsumb, s);
      gemm_k<0><<<dim3(4, NI/64), 256, 0, stream>>>(
          wsumb, depth_v_w, nullptr, nullptr, depth_ctx, nullptr, DIM, DIM);
    }
    ln3_k<<<NI/4, 256, 0, stream>>>(cur, mem_read, (s > 0 ? depth_ctx : nullptr),
                                    rc_ln_s + (size_t)s*DIM, rc_ln_b + (size_t)s*DIM,
                                    cur_in, t_ln, nullptr);
    gemm_rc1_k<<<dim3(14, NI/128), 256, 0, stream>>>(
        t_ln, rc_w1 + (size_t)s*896*DIM, rc_b1 + (size_t)s*896, hbig, 896, DIM);
    gemm_k<3><<<dim3(4, NI/64), 256, 0, stream>>>(
        hbig, rc_w2 + (size_t)s*DIM*896, rc_b2 + (size_t)s*DIM, cur_in,
        cur_in, nullptr, DIM, 896);
    float* newcur = bank + (size_t)s*NI*DIM;
    ssmhalt_k<<<NI/4, 256, 0, stream>>>(cur_in, mem_read, depth_ctx,
                                        ssm_in_w, ssm_out_w, ssm_decay,
                                        halt_w, halt_b, mem_out_w, depth_out_w,
                                        newcur, mem_logits, depth_logits, cum_halt, s);
    cur = newcur;
  }

  // ---- router: projections -> top-k -> gather lists ----
  thin70_k<<<(NI*70 + 255)/256, 256, 0, stream>>>(
      cur, sub_w, sub_b, gate_w, gate_b, budget_w, budget_b, S72);
  topk_k<<<(NI + 255)/256, 256, 0, stream>>>(S72, sparse);
  buildlist_k<<<NEXPERT_, 256, 0, stream>>>(sparse, idxl, cnt);

  // ---- post-loop conversions into overlay (loop scratch now dead) ----
  launch_cvt(cur, cur_b, (size_t)NI*DIM, stream);
  launch_cvt(x,   x_b,   (size_t)NI*DIM, stream);
  cvtup_k<<<TOTCOL/64, 512, 0, stream>>>(exp_up, shared_up_w, aux_up_w, (short*)upb);
  launch_cvt(rf_w1, rfw1b, (size_t)3*1280*DIM, stream);
  launch_cvt(rf_w2, rfw2b, (size_t)3*DIM*1280, stream);
  launch_cvt(vc_w1, vcw1b, (size_t)2*1536*DIM, stream);
  launch_cvt(vc_w2, vcw2b, (size_t)2*DIM*1536, stream);

  // ---- experts (gathered) + shared + aux (dense): ONE launch ----
  moe7_k<<<dim3(NI/128, 182), 512, 0, stream>>>(
      cur_b, x_b, (const short*)upb, exp_down, shared_down_w, aux_down_w,
      idxl, cnt, part);
  red_k<<<(14*NI*ODIM + 255)/256, 256, 0, stream>>>(part, expert_pre, shared_pre, aux_pre);

  // ---- reflection (3 cells, 1280, bf16 MFMA) ----
  const float* rsrc = cur;
  for (int i = 0; i < 3; i++){
    ln3_k<<<NI/4, 256, 0, stream>>>(rsrc, nullptr, nullptr,
                                    rf_ln_s + (size_t)i*DIM, rf_ln_b + (size_t)i*DIM,
                                    nullptr, nullptr, t_ln_b);
    bgemm_k<0><<<dim3(1280/64, NI/128), 256, 0, stream>>>(
        (const short*)t_ln_b, (const short*)(rfw1b + (size_t)i*1280*DIM),
        rf_b1 + (size_t)i*1280, nullptr, nullptr, hb, 1280, DIM);
    bgemm_k<1><<<dim3(DIM/64, NI/128), 256, 0, stream>>>(
        (const short*)hb, (const short*)(rfw2b + (size_t)i*DIM*1280),
        rf_b2 + (size_t)i*DIM, rsrc, rbuf, nullptr, DIM, 1280);
    rsrc = rbuf;
  }

  // ---- verifier (2 cells, 1536, bf16 MFMA) ----
  const float* vsrc = cur;
  for (int i = 0; i < 2; i++){
    ln3_k<<<NI/4, 256, 0, stream>>>(vsrc, nullptr, nullptr,
                                    vc_ln_s + (size_t)i*DIM, vc_ln_b + (size_t)i*DIM,
                                    nullptr, nullptr, t_ln_b);
    bgemm_k<0><<<dim3(1536/64, NI/128), 256, 0, stream>>>(
        (const short*)t_ln_b, (const short*)(vcw1b + (size_t)i*1536*DIM),
        vc_b1 + (size_t)i*1536, nullptr, nullptr, hb, 1536, DIM);
    bgemm_k<1><<<dim3(DIM/64, NI/128), 256, 0, stream>>>(
        (const short*)hb, (const short*)(vcw2b + (size_t)i*DIM*1536),
        vc_b2 + (size_t)i*DIM, vsrc, vbuf, nullptr, DIM, 1536);
    vsrc = vbuf;
  }

  // ---- collective attention over bank ----
  gemm_k<0><<<dim3(4, NI/64), 256, 0, stream>>>(
      cur, PcT, nullptr, nullptr, q2, nullptr, DIM, DIM);
  bankattn_k<<<NI/4, 256, 0, stream>>>(q2, bank, wsumb, NSTEPS_);
  gemm_k<0><<<dim3(4, NI/64), 256, 0, stream>>>(
      wsumb, coll_v_w, nullptr, nullptr, coll_ctx, nullptr, DIM, DIM);

  // ---- verifier attention over bank ----
  gemm_k<0><<<dim3(4, NI/64), 256, 0, stream>>>(
      vbuf, PvT, nullptr, nullptr, q2, nullptr, DIM, DIM);
  bankattn_k<<<NI/4, 256, 0, stream>>>(q2, bank, wsumb, NSTEPS_);
  gemm_k<0><<<dim3(4, NI/64), 256, 0, stream>>>(
      wsumb, ver_v_w, nullptr, nullptr, ver_ctx, nullptr, DIM, DIM);

  // ---- 10-dim heads (incl. base) ----
  heads_k<<<(NI*50 + 255)/256, 256, 0, stream>>>(
      rbuf, coll_ctx, ver_ctx, vbuf, x,
      reflect_out_w, coll_out_w, ver_out_w, correction_out_w, Wm, bvec,
      reflect10, coll10, ver10, corr10, base10);

  // ---- final combine ----
  final_k<<<(NI+255)/256, 256, 0, stream>>>(
      x, cur, vbuf, coll_ctx, ver_ctx,
      base10, shared_pre, aux_pre, expert_pre, sparse,
      mem_logits, depth_logits, reflect10, coll10, ver10, corr10,
      shared_ln_s, shared_ln_b, aux_ln_s, aux_ln_b, exp_ln_s, exp_ln_b,
      aux_gate_w, aux_gate_b, ver_gate_w, ver_gate_b, revisit_w, revisit_b,
      shared_scale, mix, out);
}